// Round 14
// baseline (417.136 us; speedup 1.0000x reference)
//
#include <hip/hip_runtime.h>
#include <math.h>

#define H 64
#define NODE_IN 128
#define EDGE_IN 16
#define N_NODES 40000
#define N_EDGES 80000
#define N_GRAPHS 256
#define READOUT 1024
#define D2 128   // 2H
#define QS 256   // 4H
#define EPB 128  // edges per block (edge_mfma)

typedef unsigned short u16;
typedef __attribute__((ext_vector_type(8))) short bf16x8;
typedef __attribute__((ext_vector_type(4))) float f32x4;
#define MFMA16(a,b,c) __builtin_amdgcn_mfma_f32_16x16x32_bf16(a,b,c,0,0,0)

// split-bf16 device globals
__device__ u16 d_xhi[N_NODES*H];
__device__ u16 d_xlo[N_NODES*H];
// [o][c] layout (o<64 output, c<1088 reduction): c<1024 -> We[((c>>4)*64+o)*16+(c&15)],
// c>=1024 -> be[(c-1024)*64+o].
__device__ u16 d_we3T_hi[64*1088];
__device__ u16 d_we3T_lo[64*1088];
__device__ u16 d_bcT_hi[256*128];
__device__ u16 d_bcT_lo[256*128];

__device__ __forceinline__ float sigmoidf_(float x){ return 1.0f/(1.0f + expf(-x)); }

__device__ __forceinline__ u16 bf_hi(float x){
  union { float f; unsigned u; } c; c.f = x;
  unsigned r = (c.u + 0x7FFFu + ((c.u >> 16) & 1u)) >> 16;
  return (u16)r;
}
__device__ __forceinline__ float bf_f(u16 h){
  union { unsigned u; float f; } c; c.u = ((unsigned)h) << 16; return c.f;
}
__device__ __forceinline__ u16 bf_lo(float x, u16 hi){ return bf_hi(x - bf_f(hi)); }

// XOR-swizzled byte offset for [row][64 u16] tiles (128-B rows).
__device__ __forceinline__ int swz(int row, int kq){   // kq = bf16x8 group (0..7)
  return (row*128 + kq*16) ^ ((row & 7) << 4);
}

// trunc-split 8 f32 -> hi/lo bf16x8 (hi = trunc, lo = rne of remainder)
__device__ __forceinline__ void split8(const float* Z, bf16x8& hv, bf16x8& lv){
  union { bf16x8 v; u16 u[8]; } hh, ll;
  #pragma unroll
  for (int k = 0; k < 8; ++k){
    union { float f; unsigned u; } cz; cz.f = Z[k];
    hh.u[k] = (u16)(cz.u >> 16);
    union { unsigned u; float f; } hf; hf.u = cz.u & 0xFFFF0000u;
    union { float f; unsigned u; } rz; rz.f = Z[k] - hf.f;
    ll.u[k] = (u16)(rz.u >> 16);
  }
  hv = hh.v; lv = ll.v;
}

// ==================== weight packs (once per launch) ====================
__global__ __launch_bounds__(256) void pack_we3T(
    const float* __restrict__ We, const float* __restrict__ be){
  int i = blockIdx.x*256 + threadIdx.x;     // 69632 = 64*1088
  int o = i / 1088, c = i % 1088;
  float v;
  if (c < 1024){
    int hh = c >> 4, k = c & 15;
    v = We[(size_t)(hh*64 + o)*EDGE_IN + k];
  } else {
    v = be[(size_t)(c - 1024)*64 + o];
  }
  u16 hi = bf_hi(v);
  d_we3T_hi[i] = hi;
  d_we3T_lo[i] = bf_lo(v, hi);
}

__global__ __launch_bounds__(256) void pack_bcT(
    const float* __restrict__ Wih, const float* __restrict__ Whh){
  int i = blockIdx.x*256 + threadIdx.x;     // 32768
  int k = i >> 8, c = i & 255;
  float v;
  if (c < 128){
    v = (k < 64) ? Wih[(size_t)c*H + k] : Whh[(size_t)c*H + (k-64)];
  } else if (c < 192){
    int d = c - 128;
    v = (k < 64) ? Wih[(size_t)(128+d)*H + k] : 0.f;
  } else {
    int d = c - 192;
    v = (k < 64) ? 0.f : Whh[(size_t)(128+d)*H + (k-64)];
  }
  u16 hi = bf_hi(v);
  d_bcT_hi[c*128 + k] = hi;
  d_bcT_lo[c*128 + k] = bf_lo(v, hi);
}

// ==================== zero fill ====================
__global__ __launch_bounds__(256) void zero_buf(float4* __restrict__ p, int n4){
  int i = blockIdx.x*256 + threadIdx.x;
  int stride = gridDim.x*256;
  for (; i < n4; i += stride) p[i] = make_float4(0.f,0.f,0.f,0.f);
}

// ==================== proj GEMM ====================
__global__ __launch_bounds__(256) void proj_mm(
    const float* __restrict__ nf, const float* __restrict__ Wp,
    const float* __restrict__ bp, float* __restrict__ x0, float* __restrict__ h){
  __shared__ float A_s[NODE_IN][64];
  __shared__ float B_s[NODE_IN][64];
  int t = threadIdx.x;
  int nb = blockIdx.x * 64;
  #pragma unroll
  for (int p = 0; p < 8; ++p){
    int idx = p*256 + t;
    int n = idx >> 5, k4 = idx & 31;
    float4 v = ((const float4*)(nf + (size_t)(nb+n)*NODE_IN))[k4];
    int base = (((n>>2) ^ (k4 & 15)) << 2) + (n & 3);
    A_s[k4*4+0][base]=v.x; A_s[k4*4+1][base]=v.y;
    A_s[k4*4+2][base]=v.z; A_s[k4*4+3][base]=v.w;
  }
  #pragma unroll
  for (int p = 0; p < 8; ++p){
    int idx = p*256 + t;
    int c = idx & 63, k4 = idx >> 6;
    float4 v = ((const float4*)(Wp + (size_t)c*NODE_IN))[k4];
    B_s[k4*4+0][c]=v.x; B_s[k4*4+1][c]=v.y; B_s[k4*4+2][c]=v.z; B_s[k4*4+3][c]=v.w;
  }
  __syncthreads();
  int eg = t & 15, cg = t >> 4;
  float acc[4][4] = {};
  #pragma unroll 4
  for (int k = 0; k < NODE_IN; ++k){
    int s = (k >> 2) & 15;
    float4 a = *(const float4*)&A_s[k][(eg ^ s) << 2];
    float4 b = *(const float4*)&B_s[k][cg*4];
    float av[4] = {a.x,a.y,a.z,a.w};
    float bv[4] = {b.x,b.y,b.z,b.w};
    #pragma unroll
    for (int j = 0; j < 4; ++j)
      #pragma unroll
      for (int c = 0; c < 4; ++c) acc[j][c] += av[j]*bv[c];
  }
  float4 bb = ((const float4*)bp)[cg];
  float bv[4] = {bb.x,bb.y,bb.z,bb.w};
  #pragma unroll
  for (int j = 0; j < 4; ++j){
    int n = nb + eg*4 + j;
    float o[4];
    #pragma unroll
    for (int c = 0; c < 4; ++c) o[c] = fmaxf(acc[j][c]+bv[c], 0.f);
    *(float4*)(x0 + (size_t)n*H + cg*4) = make_float4(o[0],o[1],o[2],o[3]);
    *(float4*)(h  + (size_t)n*H + cg*4) = make_float4(o[0],o[1],o[2],o[3]);
    u16 hs[4], ls[4];
    #pragma unroll
    for (int c = 0; c < 4; ++c){ hs[c] = bf_hi(o[c]); ls[c] = bf_lo(o[c], hs[c]); }
    *(ushort4*)&d_xhi[(size_t)n*H + cg*4] = make_ushort4(hs[0],hs[1],hs[2],hs[3]);
    *(ushort4*)&d_xlo[(size_t)n*H + cg*4] = make_ushort4(ls[0],ls[1],ls[2],ls[3]);
  }
}

// ==================== fused edge message: Z_aug GEMM, 128 edges/block ====
// msg[e][o] = Z_aug[e] @ B3[:,o], K=1088. Per wave: TWO 16-edge A-tiles
// (ea = w*32+m, eb = ea+16) sharing the same B fragments -> 48 MFMA and
// 8 independent acc chains per barrier interval. B dbuf, 1 barrier/chunk.
__global__ __launch_bounds__(256) void edge_mfma(
    const float* __restrict__ xf, const float* __restrict__ ef,
    const int* __restrict__ src, const int* __restrict__ dst,
    float* __restrict__ agg){
  __shared__ __align__(16) char smem[32768];    // B dbuf: 2 x (8K hi + 8K lo)
  __shared__ __align__(16) float x_s[EPB][68];  // 34816 B; msg overlay at flush
  __shared__ int src_s[EPB], dst_s[EPB];
  float* msg_s = (float*)x_s;

  int t = threadIdx.x;
  int w = t >> 6, lane = t & 63;
  int m = lane & 15, kq = lane >> 4;
  int ebase = blockIdx.x * EPB;
  int e0 = t >> 2, j4 = t & 3;                  // B staging identity
  if (t < EPB){ src_s[t] = src[ebase + t]; dst_s[t] = dst[ebase + t]; }
  { // stage B chunk 0 -> buf0 (independent of src_s)
    const u16* gh = d_we3T_hi + (size_t)e0*1088 + j4*16;
    const u16* gl = d_we3T_lo + (size_t)e0*1088 + j4*16;
    int b0 = swz(e0, 2*j4), b1 = swz(e0, 2*j4+1);
    *(bf16x8*)(smem + b0)        = *(const bf16x8*)gh;
    *(bf16x8*)(smem + b1)        = *(const bf16x8*)(gh+8);
    *(bf16x8*)(smem + 8192 + b0) = *(const bf16x8*)gl;
    *(bf16x8*)(smem + 8192 + b1) = *(const bf16x8*)(gl+8);
  }
  __syncthreads();   // src_s visible
  { // stage x rows: 2 threads/row, 32 floats each (coalesced float4)
    int row = t >> 1, half = t & 1;
    const float4* px = (const float4*)(xf + (size_t)src_s[row]*H + half*32);
    float* xr = &x_s[row][half*32];
    #pragma unroll
    for (int q = 0; q < 8; ++q) ((float4*)xr)[q] = px[q];
  }
  int ea = w*32 + m, eb = ea + 16;
  float ef8a[8], ef8b[8];
  {
    const float4* pa = (const float4*)(ef + (size_t)(ebase+ea)*EDGE_IN + (kq&1)*8);
    const float4* pb = (const float4*)(ef + (size_t)(ebase+eb)*EDGE_IN + (kq&1)*8);
    float4 a0 = pa[0], a1 = pa[1], b0 = pb[0], b1 = pb[1];
    ef8a[0]=a0.x; ef8a[1]=a0.y; ef8a[2]=a0.z; ef8a[3]=a0.w;
    ef8a[4]=a1.x; ef8a[5]=a1.y; ef8a[6]=a1.z; ef8a[7]=a1.w;
    ef8b[0]=b0.x; ef8b[1]=b0.y; ef8b[2]=b0.z; ef8b[3]=b0.w;
    ef8b[4]=b1.x; ef8b[5]=b1.y; ef8b[6]=b1.z; ef8b[7]=b1.w;
  }
  __syncthreads();   // x_s + B0 visible

  int hsel = kq >> 1;
  f32x4 acca[4], accb[4];
  #pragma unroll
  for (int i = 0; i < 4; ++i){
    acca[i] = (f32x4){0.f,0.f,0.f,0.f};
    accb[i] = (f32x4){0.f,0.f,0.f,0.f};
  }

  #pragma unroll 2
  for (int ci = 0; ci < 16; ++ci){
    // prefetch chunk ci+1 (chunk 16 = bias cols) into regs
    bf16x8 pbh0, pbh1, pbl0, pbl1;
    {
      const u16* gh = d_we3T_hi + (size_t)e0*1088 + (ci+1)*64 + j4*16;
      const u16* gl = d_we3T_lo + (size_t)e0*1088 + (ci+1)*64 + j4*16;
      pbh0 = *(const bf16x8*)gh; pbh1 = *(const bf16x8*)(gh+8);
      pbl0 = *(const bf16x8*)gl; pbl1 = *(const bf16x8*)(gl+8);
    }
    // A fragments for both edge tiles
    float xa0 = x_s[ea][ci*4 + hsel],     xa1 = x_s[ea][ci*4 + 2 + hsel];
    float xb0 = x_s[eb][ci*4 + hsel],     xb1 = x_s[eb][ci*4 + 2 + hsel];
    float Za0[8], Za1[8], Zb0[8], Zb1[8];
    #pragma unroll
    for (int j = 0; j < 8; ++j){
      Za0[j] = xa0*ef8a[j]; Za1[j] = xa1*ef8a[j];
      Zb0[j] = xb0*ef8b[j]; Zb1[j] = xb1*ef8b[j];
    }
    bf16x8 aah0, aal0, aah1, aal1, bah0, bal0, bah1, bal1;
    split8(Za0, aah0, aal0); split8(Za1, aah1, aal1);
    split8(Zb0, bah0, bal0); split8(Zb1, bah1, bal1);
    // MFMA from LDS buf[ci&1]; B fragments shared by both tiles
    {
      char* BhC = smem + (ci & 1)*16384;
      char* BlC = BhC + 8192;
      #pragma unroll
      for (int nt = 0; nt < 4; ++nt){
        int rb = nt*16 + m;
        int c0 = swz(rb, kq), c1 = c0 ^ 64;
        bf16x8 bh0 = *(const bf16x8*)(BhC + c0);
        bf16x8 bh1 = *(const bf16x8*)(BhC + c1);
        bf16x8 bl0 = *(const bf16x8*)(BlC + c0);
        bf16x8 bl1 = *(const bf16x8*)(BlC + c1);
        acca[nt] = MFMA16(aah0, bh0, acca[nt]);
        accb[nt] = MFMA16(bah0, bh0, accb[nt]);
        acca[nt] = MFMA16(aah1, bh1, acca[nt]);
        accb[nt] = MFMA16(bah1, bh1, accb[nt]);
        acca[nt] = MFMA16(aah0, bl0, acca[nt]);
        accb[nt] = MFMA16(bah0, bl0, accb[nt]);
        acca[nt] = MFMA16(aah1, bl1, acca[nt]);
        accb[nt] = MFMA16(bah1, bl1, accb[nt]);
        acca[nt] = MFMA16(aal0, bh0, acca[nt]);
        accb[nt] = MFMA16(bal0, bh0, accb[nt]);
        acca[nt] = MFMA16(aal1, bh1, acca[nt]);
        accb[nt] = MFMA16(bal1, bh1, accb[nt]);
      }
    }
    // write prefetched B -> other buffer
    {
      char* BhN = smem + ((ci+1) & 1)*16384;
      char* BlN = BhN + 8192;
      int b0 = swz(e0, 2*j4), b1 = swz(e0, 2*j4+1);
      *(bf16x8*)(BhN + b0) = pbh0;
      *(bf16x8*)(BhN + b1) = pbh1;
      *(bf16x8*)(BlN + b0) = pbl0;
      *(bf16x8*)(BlN + b1) = pbl1;
    }
    __syncthreads();
  }
  { // bias chunk (ci=16) from buf0
    float xba[16], xbb[16];
    {
      const float4* q0 = (const float4*)&x_s[ea][kq*8];
      const float4* q1 = (const float4*)&x_s[ea][32 + kq*8];
      const float4* q2 = (const float4*)&x_s[eb][kq*8];
      const float4* q3 = (const float4*)&x_s[eb][32 + kq*8];
      float4 a=q0[0], b=q0[1], c=q1[0], d=q1[1];
      float4 e=q2[0], f=q2[1], g=q3[0], hh=q3[1];
      xba[0]=a.x; xba[1]=a.y; xba[2]=a.z; xba[3]=a.w;
      xba[4]=b.x; xba[5]=b.y; xba[6]=b.z; xba[7]=b.w;
      xba[8]=c.x; xba[9]=c.y; xba[10]=c.z; xba[11]=c.w;
      xba[12]=d.x; xba[13]=d.y; xba[14]=d.z; xba[15]=d.w;
      xbb[0]=e.x; xbb[1]=e.y; xbb[2]=e.z; xbb[3]=e.w;
      xbb[4]=f.x; xbb[5]=f.y; xbb[6]=f.z; xbb[7]=f.w;
      xbb[8]=g.x; xbb[9]=g.y; xbb[10]=g.z; xbb[11]=g.w;
      xbb[12]=hh.x; xbb[13]=hh.y; xbb[14]=hh.z; xbb[15]=hh.w;
    }
    bf16x8 aah0, aal0, aah1, aal1, bah0, bal0, bah1, bal1;
    split8(xba,     aah0, aal0); split8(xba + 8, aah1, aal1);
    split8(xbb,     bah0, bal0); split8(xbb + 8, bah1, bal1);
    char* BhC = smem;
    char* BlC = smem + 8192;
    #pragma unroll
    for (int nt = 0; nt < 4; ++nt){
      int rb = nt*16 + m;
      int c0 = swz(rb, kq), c1 = c0 ^ 64;
      bf16x8 bh0 = *(const bf16x8*)(BhC + c0);
      bf16x8 bh1 = *(const bf16x8*)(BhC + c1);
      bf16x8 bl0 = *(const bf16x8*)(BlC + c0);
      bf16x8 bl1 = *(const bf16x8*)(BlC + c1);
      acca[nt] = MFMA16(aah0, bh0, acca[nt]);
      accb[nt] = MFMA16(bah0, bh0, accb[nt]);
      acca[nt] = MFMA16(aah1, bh1, acca[nt]);
      accb[nt] = MFMA16(bah1, bh1, accb[nt]);
      acca[nt] = MFMA16(aah0, bl0, acca[nt]);
      accb[nt] = MFMA16(bah0, bl0, accb[nt]);
      acca[nt] = MFMA16(aah1, bl1, acca[nt]);
      accb[nt] = MFMA16(bah1, bl1, accb[nt]);
      acca[nt] = MFMA16(aal0, bh0, acca[nt]);
      accb[nt] = MFMA16(bal0, bh0, accb[nt]);
      acca[nt] = MFMA16(aal1, bh1, acca[nt]);
      accb[nt] = MFMA16(bal1, bh1, accb[nt]);
    }
  }
  __syncthreads();   // all x_s reads done before msg overlay
  // epilogue: stage msg to LDS (overlay), coalesced atomic flush
  #pragma unroll
  for (int nt = 0; nt < 4; ++nt){
    int o = nt*16 + m;
    #pragma unroll
    for (int r = 0; r < 4; ++r){
      int eea = w*32 + kq*4 + r;
      int eeb = eea + 16;
      msg_s[eea*64 + (o ^ ((eea & 7) << 2))] = acca[nt][r];
      msg_s[eeb*64 + (o ^ ((eeb & 7) << 2))] = accb[nt][r];
    }
  }
  __syncthreads();
  #pragma unroll
  for (int r = 0; r < 32; ++r){
    int ee = w*32 + r;
    atomicAdd(&agg[(size_t)dst_s[ee]*H + lane],
              msg_s[ee*64 + (lane ^ ((ee & 7) << 2))]);
  }
}

// ==================== GRU GEMM (MFMA split-bf16) + fused GRU epilogue ====
// Also zeroes its agg rows after reading them (replaces per-step zero fill).
__global__ __launch_bounds__(256) void gru_mm_mfma(
    float* __restrict__ agg, const float* __restrict__ bconv,
    float* __restrict__ h, const float* __restrict__ gbih,
    const float* __restrict__ gbhh){
  __shared__ u16 Ah[64][40], Al[64][40];
  __shared__ u16 Bh[256][40], Bl_[256][40];
  __shared__ float bih_s[192], bhh_s[192];
  int t = threadIdx.x;
  int w = t >> 6, lane = t & 63;
  int nb = blockIdx.x * 64;
  if (t < 192){ bih_s[t] = gbih[t]; bhh_s[t] = gbhh[t]; }
  int m = lane & 15, kj = (lane >> 4) * 8;
  f32x4 acc[16];
  #pragma unroll
  for (int i = 0; i < 16; ++i) acc[i] = (f32x4){0.f,0.f,0.f,0.f};
  for (int kc = 0; kc < 4; ++kc){
    __syncthreads();
    {
      int n = t >> 2, q = t & 3;
      if (kc < 2){
        float* sp = agg + (size_t)(nb+n)*H + kc*32 + q*8;
        float4 v0 = *(const float4*)sp;
        float4 v1 = *(const float4*)(sp + 4);
        float4 b0 = *(const float4*)&bconv[kc*32 + q*8];
        float4 b1 = *(const float4*)&bconv[kc*32 + q*8 + 4];
        *(float4*)sp       = make_float4(0.f,0.f,0.f,0.f);
        *(float4*)(sp + 4) = make_float4(0.f,0.f,0.f,0.f);
        float vals[8] = { fmaxf(v0.x+b0.x,0.f), fmaxf(v0.y+b0.y,0.f),
                          fmaxf(v0.z+b0.z,0.f), fmaxf(v0.w+b0.w,0.f),
                          fmaxf(v1.x+b1.x,0.f), fmaxf(v1.y+b1.y,0.f),
                          fmaxf(v1.z+b1.z,0.f), fmaxf(v1.w+b1.w,0.f) };
        union { bf16x8 v; u16 u[8]; } ph, pl;
        #pragma unroll
        for (int j = 0; j < 8; ++j){
          u16 hi = bf_hi(vals[j]);
          ph.u[j] = hi; pl.u[j] = bf_lo(vals[j], hi);
        }
        *(bf16x8*)&Ah[n][q*8] = ph.v;
        *(bf16x8*)&Al[n][q*8] = pl.v;
      } else {
        int gofs = (nb+n)*H + (kc-2)*32 + q*8;
        *(bf16x8*)&Ah[n][q*8] = *(const bf16x8*)&d_xhi[gofs];
        *(bf16x8*)&Al[n][q*8] = *(const bf16x8*)&d_xlo[gofs];
      }
    }
    #pragma unroll
    for (int qq = 0; qq < 4; ++qq){
      int gofs = t*128 + kc*32 + qq*8;
      *(bf16x8*)&Bh[t][qq*8]  = *(const bf16x8*)&d_bcT_hi[gofs];
      *(bf16x8*)&Bl_[t][qq*8] = *(const bf16x8*)&d_bcT_lo[gofs];
    }
    __syncthreads();
    bf16x8 ah = *(const bf16x8*)&Ah[w*16 + m][kj];
    bf16x8 al = *(const bf16x8*)&Al[w*16 + m][kj];
    #pragma unroll
    for (int nt = 0; nt < 16; ++nt){
      bf16x8 bh = *(const bf16x8*)&Bh[nt*16 + m][kj];
      bf16x8 bl = *(const bf16x8*)&Bl_[nt*16 + m][kj];
      acc[nt] = MFMA16(ah, bh, acc[nt]);
      acc[nt] = MFMA16(ah, bl, acc[nt]);
      acc[nt] = MFMA16(al, bh, acc[nt]);
    }
  }
  int q4 = lane >> 4, col0 = lane & 15;
  #pragma unroll
  for (int r = 0; r < 4; ++r){
    int node = nb + w*16 + q4*4 + r;
    #pragma unroll
    for (int j = 0; j < 4; ++j){
      int d = col0 + 16*j;
      float rg = sigmoidf_(acc[j][r]   + bih_s[d]      + bhh_s[d]);
      float z  = sigmoidf_(acc[4+j][r] + bih_s[64+d]   + bhh_s[64+d]);
      float nn = tanhf(acc[8+j][r] + bih_s[128+d] + rg*(acc[12+j][r] + bhh_s[128+d]));
      size_t off = (size_t)node*H + d;
      float hv = h[off];
      float hn = (1.f - z)*nn + z*hv;
      h[off] = hn;
      u16 hb = bf_hi(hn);
      d_xhi[off] = hb;
      d_xlo[off] = bf_lo(hn, hb);
    }
  }
}

// ==================== Bl2 pack ====================
__global__ __launch_bounds__(256) void build_bl2(
    const float* __restrict__ Wih, const float* __restrict__ Whh,
    float* __restrict__ Bl2){
  int i = blockIdx.x*256 + threadIdx.x;   // 196608
  int k = i >> 9, c = i & 511;
  int d = c >> 2, gate = c & 3;
  int row = gate*128 + d;
  float v = (k < 256) ? Wih[(size_t)row*QS + k] : Whh[(size_t)row*D2 + (k-256)];
  Bl2[i] = v;
}

// ==================== fused LSTM cell ====================
__global__ __launch_bounds__(128) void lstm_fused(
    const float* __restrict__ qstar, const float* __restrict__ Bl2,
    const float* __restrict__ bih, const float* __restrict__ bhh,
    float* __restrict__ hl, float* __restrict__ cl){
  __shared__ float A_s[384];
  int g = blockIdx.x, t = threadIdx.x;
  A_s[t]       = qstar[(size_t)g*QS + t];
  A_s[128 + t] = qstar[(size_t)g*QS + 128 + t];
  A_s[256 + t] = hl[(size_t)g*D2 + t];
  __syncthreads();
  float ai = 0.f, af = 0.f, ag = 0.f, ao = 0.f;
  const float* bp = Bl2 + 4*t;
  #pragma unroll 8
  for (int k = 0; k < 384; ++k){
    float a = A_s[k];
    float4 b = *(const float4*)(bp + (size_t)k*512);
    ai += a*b.x; af += a*b.y; ag += a*b.z; ao += a*b.w;
  }
  float iv = ai + bih[t]       + bhh[t];
  float fv = af + bih[128 + t] + bhh[128 + t];
  float gv = ag + bih[256 + t] + bhh[256 + t];
  float ov = ao + bih[384 + t] + bhh[384 + t];
  float c = sigmoidf_(fv)*cl[(size_t)g*D2 + t] + sigmoidf_(iv)*tanhf(gv);
  float hn = sigmoidf_(ov)*tanhf(c);
  cl[(size_t)g*D2 + t] = c;
  hl[(size_t)g*D2 + t] = hn;
}

// ==================== attention + pooling (512 threads) ====================
__global__ __launch_bounds__(512) void attn_kernel(
    const float* __restrict__ x0, const float* __restrict__ h,
    const float* __restrict__ hl, float* __restrict__ qstar){
  __shared__ float q_s[D2];
  __shared__ float alpha_s[160];
  __shared__ float wred[8];
  __shared__ float part[8][D2];
  int g = blockIdx.x, t = threadIdx.x;
  int lane = t & 63, w = t >> 6;
  int n0 = (g*N_NODES + N_GRAPHS - 1)/N_GRAPHS;
  int n1 = ((g+1)*N_NODES + N_GRAPHS - 1)/N_GRAPHS;
  int cnt = n1 - n0;
  if (t < D2) q_s[t] = hl[(size_t)g*D2 + t];
  __syncthreads();
  float e = -1e30f;
  if (t < cnt){
    int n = n0 + t;
    const float4* xr = (const float4*)(x0 + (size_t)n*H);
    const float4* hr = (const float4*)(h  + (size_t)n*H);
    const float4* q1 = (const float4*)q_s;
    const float4* q2 = (const float4*)(q_s + H);
    float s = 0.0f;
    #pragma unroll
    for (int k4 = 0; k4 < 16; ++k4){
      float4 a = xr[k4], b = q1[k4];
      s += a.x*b.x + a.y*b.y + a.z*b.z + a.w*b.w;
    }
    #pragma unroll
    for (int k4 = 0; k4 < 16; ++k4){
      float4 a = hr[k4], b = q2[k4];
      s += a.x*b.x + a.y*b.y + a.z*b.z + a.w*b.w;
    }
    e = s;
  }
  float m = e;
  #pragma unroll
  for (int off = 32; off >= 1; off >>= 1) m = fmaxf(m, __shfl_xor(m, off));
  if (lane == 0) wred[w] = m;
  __syncthreads();
  float gm = wred[0];
  #pragma unroll
  for (int i = 1; i < 8; ++i) gm = fmaxf(gm, wred[i]);
  __syncthreads();
  float ex = (t < cnt) ? expf(e - gm) : 0.0f;
  float sm = ex;
  #pragma unroll
  for (int off = 32; off >= 1; off >>= 1) sm += __shfl_xor(sm, off);
  if (lane == 0) wred[w] = sm;
  __syncthreads();
  float denom = wred[0]+wred[1]+wred[2]+wred[3]+wred[4]+wred[5]+wred[6]+wred[7];
  if (t < cnt) alpha_s[t] = ex / denom;
  __syncthreads();
  float acc0 = 0.f, acc1 = 0.f;
  for (int i = w; i < cnt; i += 8){
    float a = alpha_s[i];
    acc0 += a * x0[(size_t)(n0+i)*H + lane];
    acc1 += a * h [(size_t)(n0+i)*H + lane];
  }
  part[w][lane]      = acc0;
  part[w][64 + lane] = acc1;
  __syncthreads();
  if (t < D2){
    float v = 0.f;
    #pragma unroll
    for (int i = 0; i < 8; ++i) v += part[i][t];
    qstar[(size_t)g*QS + t]      = q_s[t];
    qstar[(size_t)g*QS + D2 + t] = v;
  }
}

// ==================== readout ====================
__global__ __launch_bounds__(256) void out_kernel(
    const float* __restrict__ qstar, const float* __restrict__ Wsp,
    const float* __restrict__ bsp, const float* __restrict__ prelu,
    float* __restrict__ out){
  __shared__ float q_s[QS];
  int g = blockIdx.x & 255;
  int jb = blockIdx.x >> 8;
  int t = threadIdx.x;
  q_s[t] = qstar[(size_t)g*QS + t];
  __syncthreads();
  int j = jb*256 + t;
  const float4* w = (const float4*)(Wsp + (size_t)j*QS);
  const float4* q4 = (const float4*)q_s;
  float acc = bsp[j];
  #pragma unroll
  for (int k4 = 0; k4 < 64; ++k4){
    float4 wv = w[k4]; float4 qv = q4[k4];
    acc += qv.x*wv.x + qv.y*wv.y + qv.z*wv.z + qv.w*wv.w;
  }
  float pw = prelu[0];
  out[(size_t)g*READOUT + j] = (acc >= 0.0f) ? acc : pw*acc;
}

extern "C" void kernel_launch(void* const* d_in, const int* in_sizes, int n_in,
                              void* d_out, int out_size, void* d_ws, size_t ws_size,
                              hipStream_t stream) {
  const float* node_feats = (const float*)d_in[0];
  const float* edge_feats = (const float*)d_in[1];
  const int*   esrc       = (const int*)d_in[2];
  const int*   edst       = (const int*)d_in[3];
  const float* Wproj = (const float*)d_in[5];
  const float* bproj = (const float*)d_in[6];
  const float* Wedge = (const float*)d_in[7];
  const float* bedge = (const float*)d_in[8];
  const float* bconv = (const float*)d_in[9];
  const float* gWih  = (const float*)d_in[10];
  const float* gWhh  = (const float*)d_in[11];
  const float* gbih  = (const float*)d_in[12];
  const float* gbhh  = (const float*)d_in[13];
  const float* lWih  = (const float*)d_in[14];
  const float* lWhh  = (const float*)d_in[15];
  const float* lbih  = (const float*)d_in[16];
  const float* lbhh  = (const float*)d_in[17];
  const float* Wsp   = (const float*)d_in[18];
  const float* bsp   = (const float*)d_in[19];
  const float* prelu = (const float*)d_in[20];

  float* ws    = (float*)d_ws;
  float* x0    = ws;                     // 2,560,000
  float* h     = ws + 2560000;           // 2,560,000
  float* agg   = ws + 5120000;           // 2,560,000
  float* qstar = ws + 7680000;           // 65,536
  float* hl    = qstar + 65536;          // 32,768
  float* cl    = hl + 32768;             // 32,768
  float* Bl2   = agg;                    // s2s phase reuses dead agg (196,608)

  hipMemsetAsync(qstar, 0, (65536 + 32768 + 32768)*sizeof(float), stream);

  pack_we3T<<<272, 256, 0, stream>>>(Wedge, bedge);
  pack_bcT<<<128, 256, 0, stream>>>(gWih, gWhh);

  proj_mm<<<N_NODES/64, 256, 0, stream>>>(node_feats, Wproj, bproj, x0, h);

  for (int s = 0; s < 3; ++s){
    if (s == 0)
      zero_buf<<<2048, 256, 0, stream>>>((float4*)agg, N_NODES*H/4);
    edge_mfma<<<N_EDGES/EPB, 256, 0, stream>>>(h, edge_feats, esrc, edst, agg);
    gru_mm_mfma<<<N_NODES/64, 256, 0, stream>>>(agg, bconv, h, gbih, gbhh);  // zeroes agg
  }

  build_bl2<<<768, 256, 0, stream>>>(lWih, lWhh, Bl2);

  for (int s = 0; s < 3; ++s){
    lstm_fused<<<N_GRAPHS, 128, 0, stream>>>(qstar, Bl2, lbih, lbhh, hl, cl);
    attn_kernel<<<N_GRAPHS, 512, 0, stream>>>(x0, h, hl, qstar);
  }

  out_kernel<<<4*N_GRAPHS, 256, 0, stream>>>(qstar, Wsp, bsp, prelu, (float*)d_out);
}

// Round 15
// 386.118 us; speedup vs baseline: 1.0803x; 1.0803x over previous
//
#include <hip/hip_runtime.h>
#include <math.h>

#define H 64
#define NODE_IN 128
#define EDGE_IN 16
#define N_NODES 40000
#define N_EDGES 80000
#define N_GRAPHS 256
#define READOUT 1024
#define D2 128   // 2H
#define QS 256   // 4H

typedef unsigned short u16;
typedef __attribute__((ext_vector_type(8))) short bf16x8;
typedef __attribute__((ext_vector_type(4))) float f32x4;
#define MFMA16(a,b,c) __builtin_amdgcn_mfma_f32_16x16x32_bf16(a,b,c,0,0,0)

// split-bf16 device globals
__device__ u16 d_xhi[N_NODES*H];
__device__ u16 d_xlo[N_NODES*H];
// [o][c] layout (o<64 output, c<1088 reduction): c<1024 -> We[((c>>4)*64+o)*16+(c&15)],
// c>=1024 -> be[(c-1024)*64+o].
__device__ u16 d_we3T_hi[64*1088];
__device__ u16 d_we3T_lo[64*1088];
__device__ u16 d_bcT_hi[256*128];
__device__ u16 d_bcT_lo[256*128];

__device__ __forceinline__ float sigmoidf_(float x){ return 1.0f/(1.0f + expf(-x)); }

__device__ __forceinline__ u16 bf_hi(float x){
  union { float f; unsigned u; } c; c.f = x;
  unsigned r = (c.u + 0x7FFFu + ((c.u >> 16) & 1u)) >> 16;
  return (u16)r;
}
__device__ __forceinline__ float bf_f(u16 h){
  union { unsigned u; float f; } c; c.u = ((unsigned)h) << 16; return c.f;
}
__device__ __forceinline__ u16 bf_lo(float x, u16 hi){ return bf_hi(x - bf_f(hi)); }

// XOR-swizzled byte offset for [row][64 u16] tiles (128-B rows).
__device__ __forceinline__ int swz(int row, int kq){   // kq = bf16x8 group (0..7)
  return (row*128 + kq*16) ^ ((row & 7) << 4);
}

// trunc-split 8 f32 -> hi/lo bf16x8
__device__ __forceinline__ void split8(const float* Z, bf16x8& hv, bf16x8& lv){
  union { bf16x8 v; u16 u[8]; } hh, ll;
  #pragma unroll
  for (int k = 0; k < 8; ++k){
    union { float f; unsigned u; } cz; cz.f = Z[k];
    hh.u[k] = (u16)(cz.u >> 16);
    union { unsigned u; float f; } hf; hf.u = cz.u & 0xFFFF0000u;
    union { float f; unsigned u; } rz; rz.f = Z[k] - hf.f;
    ll.u[k] = (u16)(rz.u >> 16);
  }
  hv = hh.v; lv = ll.v;
}

// ==================== weight packs (once per launch) ====================
__global__ __launch_bounds__(256) void pack_we3T(
    const float* __restrict__ We, const float* __restrict__ be){
  int i = blockIdx.x*256 + threadIdx.x;     // 69632 = 64*1088
  int o = i / 1088, c = i % 1088;
  float v;
  if (c < 1024){
    int hh = c >> 4, k = c & 15;
    v = We[(size_t)(hh*64 + o)*EDGE_IN + k];
  } else {
    v = be[(size_t)(c - 1024)*64 + o];
  }
  u16 hi = bf_hi(v);
  d_we3T_hi[i] = hi;
  d_we3T_lo[i] = bf_lo(v, hi);
}

__global__ __launch_bounds__(256) void pack_bcT(
    const float* __restrict__ Wih, const float* __restrict__ Whh){
  int i = blockIdx.x*256 + threadIdx.x;     // 32768
  int k = i >> 8, c = i & 255;
  float v;
  if (c < 128){
    v = (k < 64) ? Wih[(size_t)c*H + k] : Whh[(size_t)c*H + (k-64)];
  } else if (c < 192){
    int d = c - 128;
    v = (k < 64) ? Wih[(size_t)(128+d)*H + k] : 0.f;
  } else {
    int d = c - 192;
    v = (k < 64) ? 0.f : Whh[(size_t)(128+d)*H + (k-64)];
  }
  u16 hi = bf_hi(v);
  d_bcT_hi[c*128 + k] = hi;
  d_bcT_lo[c*128 + k] = bf_lo(v, hi);
}

// ==================== zero fill ====================
__global__ __launch_bounds__(256) void zero_buf(float4* __restrict__ p, int n4){
  int i = blockIdx.x*256 + threadIdx.x;
  int stride = gridDim.x*256;
  for (; i < n4; i += stride) p[i] = make_float4(0.f,0.f,0.f,0.f);
}

// ==================== proj GEMM ====================
__global__ __launch_bounds__(256) void proj_mm(
    const float* __restrict__ nf, const float* __restrict__ Wp,
    const float* __restrict__ bp, float* __restrict__ x0, float* __restrict__ h){
  __shared__ float A_s[NODE_IN][64];
  __shared__ float B_s[NODE_IN][64];
  int t = threadIdx.x;
  int nb = blockIdx.x * 64;
  #pragma unroll
  for (int p = 0; p < 8; ++p){
    int idx = p*256 + t;
    int n = idx >> 5, k4 = idx & 31;
    float4 v = ((const float4*)(nf + (size_t)(nb+n)*NODE_IN))[k4];
    int base = (((n>>2) ^ (k4 & 15)) << 2) + (n & 3);
    A_s[k4*4+0][base]=v.x; A_s[k4*4+1][base]=v.y;
    A_s[k4*4+2][base]=v.z; A_s[k4*4+3][base]=v.w;
  }
  #pragma unroll
  for (int p = 0; p < 8; ++p){
    int idx = p*256 + t;
    int c = idx & 63, k4 = idx >> 6;
    float4 v = ((const float4*)(Wp + (size_t)c*NODE_IN))[k4];
    B_s[k4*4+0][c]=v.x; B_s[k4*4+1][c]=v.y; B_s[k4*4+2][c]=v.z; B_s[k4*4+3][c]=v.w;
  }
  __syncthreads();
  int eg = t & 15, cg = t >> 4;
  float acc[4][4] = {};
  #pragma unroll 4
  for (int k = 0; k < NODE_IN; ++k){
    int s = (k >> 2) & 15;
    float4 a = *(const float4*)&A_s[k][(eg ^ s) << 2];
    float4 b = *(const float4*)&B_s[k][cg*4];
    float av[4] = {a.x,a.y,a.z,a.w};
    float bv[4] = {b.x,b.y,b.z,b.w};
    #pragma unroll
    for (int j = 0; j < 4; ++j)
      #pragma unroll
      for (int c = 0; c < 4; ++c) acc[j][c] += av[j]*bv[c];
  }
  float4 bb = ((const float4*)bp)[cg];
  float bv[4] = {bb.x,bb.y,bb.z,bb.w};
  #pragma unroll
  for (int j = 0; j < 4; ++j){
    int n = nb + eg*4 + j;
    float o[4];
    #pragma unroll
    for (int c = 0; c < 4; ++c) o[c] = fmaxf(acc[j][c]+bv[c], 0.f);
    *(float4*)(x0 + (size_t)n*H + cg*4) = make_float4(o[0],o[1],o[2],o[3]);
    *(float4*)(h  + (size_t)n*H + cg*4) = make_float4(o[0],o[1],o[2],o[3]);
    u16 hs[4], ls[4];
    #pragma unroll
    for (int c = 0; c < 4; ++c){ hs[c] = bf_hi(o[c]); ls[c] = bf_lo(o[c], hs[c]); }
    *(ushort4*)&d_xhi[(size_t)n*H + cg*4] = make_ushort4(hs[0],hs[1],hs[2],hs[3]);
    *(ushort4*)&d_xlo[(size_t)n*H + cg*4] = make_ushort4(ls[0],ls[1],ls[2],ls[3]);
  }
}

// ==================== fused edge message (round-13 structure, 64 edges/block) ====
__global__ __launch_bounds__(256) void edge_mfma(
    const float* __restrict__ xf, const float* __restrict__ ef,
    const int* __restrict__ src, const int* __restrict__ dst,
    float* __restrict__ agg){
  __shared__ __align__(16) char smem[32768];   // B dbuf: 2 x (8K hi + 8K lo)
  __shared__ __align__(16) float x_s[64][68];  // 17.4 KB; msg overlay at flush
  __shared__ int src_s[64], dst_s[64];
  float* msg_s = (float*)x_s;

  int t = threadIdx.x;
  int w = t >> 6, lane = t & 63;
  int m = lane & 15, kq = lane >> 4;
  int ebase = blockIdx.x * 64;
  int e0 = t >> 2, j4 = t & 3;
  if (t < 64){ src_s[t] = src[ebase + t]; dst_s[t] = dst[ebase + t]; }
  { // stage B chunk 0 -> buf0
    const u16* gh = d_we3T_hi + (size_t)e0*1088 + j4*16;
    const u16* gl = d_we3T_lo + (size_t)e0*1088 + j4*16;
    int b0 = swz(e0, 2*j4), b1 = swz(e0, 2*j4+1);
    *(bf16x8*)(smem + b0)        = *(const bf16x8*)gh;
    *(bf16x8*)(smem + b1)        = *(const bf16x8*)(gh+8);
    *(bf16x8*)(smem + 8192 + b0) = *(const bf16x8*)gl;
    *(bf16x8*)(smem + 8192 + b1) = *(const bf16x8*)(gl+8);
  }
  __syncthreads();
  { // stage x rows
    const float4* px = (const float4*)(xf + (size_t)src_s[e0]*H + j4*16);
    float4 v0=px[0], v1=px[1], v2=px[2], v3=px[3];
    float* xr = &x_s[e0][j4*16];
    *(float4*)xr      = v0;
    *(float4*)(xr+4)  = v1;
    *(float4*)(xr+8)  = v2;
    *(float4*)(xr+12) = v3;
  }
  int e = w*16 + m;
  float ef8[8];
  {
    const float4* p = (const float4*)(ef + (size_t)(ebase+e)*EDGE_IN + (kq&1)*8);
    float4 a = p[0], b = p[1];
    ef8[0]=a.x; ef8[1]=a.y; ef8[2]=a.z; ef8[3]=a.w;
    ef8[4]=b.x; ef8[5]=b.y; ef8[6]=b.z; ef8[7]=b.w;
  }
  __syncthreads();

  int hsel = kq >> 1;
  f32x4 acc[4];
  #pragma unroll
  for (int i = 0; i < 4; ++i) acc[i] = (f32x4){0.f,0.f,0.f,0.f};

  #pragma unroll 2
  for (int ci = 0; ci < 16; ++ci){
    bf16x8 pbh0, pbh1, pbl0, pbl1;
    {
      const u16* gh = d_we3T_hi + (size_t)e0*1088 + (ci+1)*64 + j4*16;
      const u16* gl = d_we3T_lo + (size_t)e0*1088 + (ci+1)*64 + j4*16;
      pbh0 = *(const bf16x8*)gh; pbh1 = *(const bf16x8*)(gh+8);
      pbl0 = *(const bf16x8*)gl; pbl1 = *(const bf16x8*)(gl+8);
    }
    float x0v = x_s[e][ci*4 + hsel];
    float x1v = x_s[e][ci*4 + 2 + hsel];
    float Z0[8], Z1[8];
    #pragma unroll
    for (int j = 0; j < 8; ++j){ Z0[j] = x0v*ef8[j]; Z1[j] = x1v*ef8[j]; }
    bf16x8 ah0, al0, ah1, al1;
    split8(Z0, ah0, al0);
    split8(Z1, ah1, al1);
    {
      char* BhC = smem + (ci & 1)*16384;
      char* BlC = BhC + 8192;
      #pragma unroll
      for (int nt = 0; nt < 4; ++nt){
        int rb = nt*16 + m;
        int c0 = swz(rb, kq), c1 = c0 ^ 64;
        bf16x8 bh0 = *(const bf16x8*)(BhC + c0);
        bf16x8 bh1 = *(const bf16x8*)(BhC + c1);
        bf16x8 bl0 = *(const bf16x8*)(BlC + c0);
        bf16x8 bl1 = *(const bf16x8*)(BlC + c1);
        acc[nt] = MFMA16(ah0, bh0, acc[nt]);
        acc[nt] = MFMA16(ah1, bh1, acc[nt]);
        acc[nt] = MFMA16(ah0, bl0, acc[nt]);
        acc[nt] = MFMA16(ah1, bl1, acc[nt]);
        acc[nt] = MFMA16(al0, bh0, acc[nt]);
        acc[nt] = MFMA16(al1, bh1, acc[nt]);
      }
    }
    {
      char* BhN = smem + ((ci+1) & 1)*16384;
      char* BlN = BhN + 8192;
      int b0 = swz(e0, 2*j4), b1 = swz(e0, 2*j4+1);
      *(bf16x8*)(BhN + b0) = pbh0;
      *(bf16x8*)(BhN + b1) = pbh1;
      *(bf16x8*)(BlN + b0) = pbl0;
      *(bf16x8*)(BlN + b1) = pbl1;
    }
    __syncthreads();
  }
  { // bias chunk (ci=16) from buf0
    float xb[16];
    {
      const float4* q0 = (const float4*)&x_s[e][kq*8];
      const float4* q1 = (const float4*)&x_s[e][32 + kq*8];
      float4 a=q0[0], b=q0[1], c=q1[0], d=q1[1];
      xb[0]=a.x; xb[1]=a.y; xb[2]=a.z; xb[3]=a.w;
      xb[4]=b.x; xb[5]=b.y; xb[6]=b.z; xb[7]=b.w;
      xb[8]=c.x; xb[9]=c.y; xb[10]=c.z; xb[11]=c.w;
      xb[12]=d.x; xb[13]=d.y; xb[14]=d.z; xb[15]=d.w;
    }
    bf16x8 ah0, al0, ah1, al1;
    split8(xb,     ah0, al0);
    split8(xb + 8, ah1, al1);
    char* BhC = smem;
    char* BlC = smem + 8192;
    #pragma unroll
    for (int nt = 0; nt < 4; ++nt){
      int rb = nt*16 + m;
      int c0 = swz(rb, kq), c1 = c0 ^ 64;
      bf16x8 bh0 = *(const bf16x8*)(BhC + c0);
      bf16x8 bh1 = *(const bf16x8*)(BhC + c1);
      bf16x8 bl0 = *(const bf16x8*)(BlC + c0);
      bf16x8 bl1 = *(const bf16x8*)(BlC + c1);
      acc[nt] = MFMA16(ah0, bh0, acc[nt]);
      acc[nt] = MFMA16(ah1, bh1, acc[nt]);
      acc[nt] = MFMA16(ah0, bl0, acc[nt]);
      acc[nt] = MFMA16(ah1, bl1, acc[nt]);
      acc[nt] = MFMA16(al0, bh0, acc[nt]);
      acc[nt] = MFMA16(al1, bh1, acc[nt]);
    }
  }
  __syncthreads();
  #pragma unroll
  for (int nt = 0; nt < 4; ++nt){
    int o = nt*16 + m;
    #pragma unroll
    for (int r = 0; r < 4; ++r){
      int ee = w*16 + kq*4 + r;
      msg_s[ee*64 + (o ^ ((ee & 7) << 2))] = acc[nt][r];
    }
  }
  __syncthreads();
  #pragma unroll
  for (int r = 0; r < 16; ++r){
    int ee = w*16 + r;
    atomicAdd(&agg[(size_t)dst_s[ee]*H + lane],
              msg_s[ee*64 + (lane ^ ((ee & 7) << 2))]);
  }
}

// ==================== GRU GEMM + fused epilogue; B chunk reg-prefetched (T14) ====
// Also zeroes its agg rows after reading them.
__global__ __launch_bounds__(256) void gru_mm_mfma(
    float* __restrict__ agg, const float* __restrict__ bconv,
    float* __restrict__ h, const float* __restrict__ gbih,
    const float* __restrict__ gbhh){
  __shared__ u16 Ah[64][40], Al[64][40];
  __shared__ u16 Bh[256][40], Bl_[256][40];
  __shared__ float bih_s[192], bhh_s[192];
  int t = threadIdx.x;
  int w = t >> 6, lane = t & 63;
  int nb = blockIdx.x * 64;
  if (t < 192){ bih_s[t] = gbih[t]; bhh_s[t] = gbhh[t]; }
  int m = lane & 15, kj = (lane >> 4) * 8;
  f32x4 acc[16];
  #pragma unroll
  for (int i = 0; i < 16; ++i) acc[i] = (f32x4){0.f,0.f,0.f,0.f};
  // prologue: issue B(0) into regs
  bf16x8 pbh[4], pbl[4];
  #pragma unroll
  for (int qq = 0; qq < 4; ++qq){
    int gofs = t*128 + qq*8;
    pbh[qq] = *(const bf16x8*)&d_bcT_hi[gofs];
    pbl[qq] = *(const bf16x8*)&d_bcT_lo[gofs];
  }
  for (int kc = 0; kc < 4; ++kc){
    __syncthreads();   // previous compute done; LDS writable
    {
      int n = t >> 2, q = t & 3;
      if (kc < 2){
        float* sp = agg + (size_t)(nb+n)*H + kc*32 + q*8;
        float4 v0 = *(const float4*)sp;
        float4 v1 = *(const float4*)(sp + 4);
        float4 b0 = *(const float4*)&bconv[kc*32 + q*8];
        float4 b1 = *(const float4*)&bconv[kc*32 + q*8 + 4];
        *(float4*)sp       = make_float4(0.f,0.f,0.f,0.f);
        *(float4*)(sp + 4) = make_float4(0.f,0.f,0.f,0.f);
        float vals[8] = { fmaxf(v0.x+b0.x,0.f), fmaxf(v0.y+b0.y,0.f),
                          fmaxf(v0.z+b0.z,0.f), fmaxf(v0.w+b0.w,0.f),
                          fmaxf(v1.x+b1.x,0.f), fmaxf(v1.y+b1.y,0.f),
                          fmaxf(v1.z+b1.z,0.f), fmaxf(v1.w+b1.w,0.f) };
        union { bf16x8 v; u16 u[8]; } ph, pl;
        #pragma unroll
        for (int j = 0; j < 8; ++j){
          u16 hi = bf_hi(vals[j]);
          ph.u[j] = hi; pl.u[j] = bf_lo(vals[j], hi);
        }
        *(bf16x8*)&Ah[n][q*8] = ph.v;
        *(bf16x8*)&Al[n][q*8] = pl.v;
      } else {
        int gofs = (nb+n)*H + (kc-2)*32 + q*8;
        *(bf16x8*)&Ah[n][q*8] = *(const bf16x8*)&d_xhi[gofs];
        *(bf16x8*)&Al[n][q*8] = *(const bf16x8*)&d_xlo[gofs];
      }
    }
    // write prefetched B chunk, then issue next chunk's loads
    #pragma unroll
    for (int qq = 0; qq < 4; ++qq){
      *(bf16x8*)&Bh[t][qq*8]  = pbh[qq];
      *(bf16x8*)&Bl_[t][qq*8] = pbl[qq];
    }
    if (kc < 3){
      #pragma unroll
      for (int qq = 0; qq < 4; ++qq){
        int gofs = t*128 + (kc+1)*32 + qq*8;
        pbh[qq] = *(const bf16x8*)&d_bcT_hi[gofs];
        pbl[qq] = *(const bf16x8*)&d_bcT_lo[gofs];
      }
    }
    __syncthreads();
    bf16x8 ah = *(const bf16x8*)&Ah[w*16 + m][kj];
    bf16x8 al = *(const bf16x8*)&Al[w*16 + m][kj];
    #pragma unroll
    for (int nt = 0; nt < 16; ++nt){
      bf16x8 bh = *(const bf16x8*)&Bh[nt*16 + m][kj];
      bf16x8 bl = *(const bf16x8*)&Bl_[nt*16 + m][kj];
      acc[nt] = MFMA16(ah, bh, acc[nt]);
      acc[nt] = MFMA16(ah, bl, acc[nt]);
      acc[nt] = MFMA16(al, bh, acc[nt]);
    }
  }
  int q4 = lane >> 4, col0 = lane & 15;
  #pragma unroll
  for (int r = 0; r < 4; ++r){
    int node = nb + w*16 + q4*4 + r;
    #pragma unroll
    for (int j = 0; j < 4; ++j){
      int d = col0 + 16*j;
      float rg = sigmoidf_(acc[j][r]   + bih_s[d]      + bhh_s[d]);
      float z  = sigmoidf_(acc[4+j][r] + bih_s[64+d]   + bhh_s[64+d]);
      float nn = tanhf(acc[8+j][r] + bih_s[128+d] + rg*(acc[12+j][r] + bhh_s[128+d]));
      size_t off = (size_t)node*H + d;
      float hv = h[off];
      float hn = (1.f - z)*nn + z*hv;
      h[off] = hn;
      u16 hb = bf_hi(hn);
      d_xhi[off] = hb;
      d_xlo[off] = bf_lo(hn, hb);
    }
  }
}

// ==================== Bl2 pack ====================
__global__ __launch_bounds__(256) void build_bl2(
    const float* __restrict__ Wih, const float* __restrict__ Whh,
    float* __restrict__ Bl2){
  int i = blockIdx.x*256 + threadIdx.x;   // 196608
  int k = i >> 9, c = i & 511;
  int d = c >> 2, gate = c & 3;
  int row = gate*128 + d;
  float v = (k < 256) ? Wih[(size_t)row*QS + k] : Whh[(size_t)row*D2 + (k-256)];
  Bl2[i] = v;
}

// ==================== fused Set2Set step: LSTM cell + attention (512 thr) ====
// Phase 1: gates = [qstar|hl] @ Bl2 via 4x96-k slices -> LDS reduce -> cell.
// Phase 2: attention with q (new hl) already in LDS.
__global__ __launch_bounds__(512) void s2s_kernel(
    const float* __restrict__ x0, const float* __restrict__ h,
    const float* __restrict__ Bl2, const float* __restrict__ lbih,
    const float* __restrict__ lbhh, float* __restrict__ hl,
    float* __restrict__ cl, float* __restrict__ qstar){
  __shared__ float A_s[384];
  __shared__ float part4[4][128][4];   // [kslice][d][gate] 8 KB
  __shared__ float q_s[D2];
  __shared__ float alpha_s[160];
  __shared__ float wred[8];
  __shared__ float part[8][D2];
  int g = blockIdx.x, t = threadIdx.x;
  int lane = t & 63, w = t >> 6;
  // stage LSTM input (OLD qstar / hl)
  if (t < 384){
    A_s[t] = (t < 256) ? qstar[(size_t)g*QS + t] : hl[(size_t)g*D2 + (t - 256)];
  }
  __syncthreads();
  { // phase 1: partial gate sums
    int d = t & 127, ks = t >> 7;
    const float* bp = Bl2 + 4*d;
    float ai = 0.f, af = 0.f, ag = 0.f, ao = 0.f;
    #pragma unroll 8
    for (int kk = 0; kk < 96; ++kk){
      int k = ks*96 + kk;
      float a = A_s[k];
      float4 b = *(const float4*)(bp + (size_t)k*512);
      ai += a*b.x; af += a*b.y; ag += a*b.z; ao += a*b.w;
    }
    *(float4*)&part4[ks][d][0] = make_float4(ai, af, ag, ao);
  }
  __syncthreads();
  if (t < D2){
    float4 p0 = *(const float4*)&part4[0][t][0];
    float4 p1 = *(const float4*)&part4[1][t][0];
    float4 p2 = *(const float4*)&part4[2][t][0];
    float4 p3 = *(const float4*)&part4[3][t][0];
    float iv = p0.x+p1.x+p2.x+p3.x + lbih[t]       + lbhh[t];
    float fv = p0.y+p1.y+p2.y+p3.y + lbih[128 + t] + lbhh[128 + t];
    float gv = p0.z+p1.z+p2.z+p3.z + lbih[256 + t] + lbhh[256 + t];
    float ov = p0.w+p1.w+p2.w+p3.w + lbih[384 + t] + lbhh[384 + t];
    float c = sigmoidf_(fv)*cl[(size_t)g*D2 + t] + sigmoidf_(iv)*tanhf(gv);
    float hn = sigmoidf_(ov)*tanhf(c);
    cl[(size_t)g*D2 + t] = c;
    hl[(size_t)g*D2 + t] = hn;
    q_s[t] = hn;
  }
  __syncthreads();
  // phase 2: attention
  int n0 = (g*N_NODES + N_GRAPHS - 1)/N_GRAPHS;
  int n1 = ((g+1)*N_NODES + N_GRAPHS - 1)/N_GRAPHS;
  int cnt = n1 - n0;
  float e = -1e30f;
  if (t < cnt){
    int n = n0 + t;
    const float4* xr = (const float4*)(x0 + (size_t)n*H);
    const float4* hr = (const float4*)(h  + (size_t)n*H);
    const float4* q1 = (const float4*)q_s;
    const float4* q2 = (const float4*)(q_s + H);
    float s = 0.0f;
    #pragma unroll
    for (int k4 = 0; k4 < 16; ++k4){
      float4 a = xr[k4], b = q1[k4];
      s += a.x*b.x + a.y*b.y + a.z*b.z + a.w*b.w;
    }
    #pragma unroll
    for (int k4 = 0; k4 < 16; ++k4){
      float4 a = hr[k4], b = q2[k4];
      s += a.x*b.x + a.y*b.y + a.z*b.z + a.w*b.w;
    }
    e = s;
  }
  float mx = e;
  #pragma unroll
  for (int off = 32; off >= 1; off >>= 1) mx = fmaxf(mx, __shfl_xor(mx, off));
  if (lane == 0) wred[w] = mx;
  __syncthreads();
  float gm = wred[0];
  #pragma unroll
  for (int i = 1; i < 8; ++i) gm = fmaxf(gm, wred[i]);
  __syncthreads();
  float ex = (t < cnt) ? expf(e - gm) : 0.0f;
  float sm = ex;
  #pragma unroll
  for (int off = 32; off >= 1; off >>= 1) sm += __shfl_xor(sm, off);
  if (lane == 0) wred[w] = sm;
  __syncthreads();
  float denom = wred[0]+wred[1]+wred[2]+wred[3]+wred[4]+wred[5]+wred[6]+wred[7];
  if (t < cnt) alpha_s[t] = ex / denom;
  __syncthreads();
  float acc0 = 0.f, acc1 = 0.f;
  for (int i = w; i < cnt; i += 8){
    float a = alpha_s[i];
    acc0 += a * x0[(size_t)(n0+i)*H + lane];
    acc1 += a * h [(size_t)(n0+i)*H + lane];
  }
  part[w][lane]      = acc0;
  part[w][64 + lane] = acc1;
  __syncthreads();
  if (t < D2){
    float v = 0.f;
    #pragma unroll
    for (int i = 0; i < 8; ++i) v += part[i][t];
    qstar[(size_t)g*QS + t]      = q_s[t];
    qstar[(size_t)g*QS + D2 + t] = v;
  }
}

// ==================== readout ====================
__global__ __launch_bounds__(256) void out_kernel(
    const float* __restrict__ qstar, const float* __restrict__ Wsp,
    const float* __restrict__ bsp, const float* __restrict__ prelu,
    float* __restrict__ out){
  __shared__ float q_s[QS];
  int g = blockIdx.x & 255;
  int jb = blockIdx.x >> 8;
  int t = threadIdx.x;
  q_s[t] = qstar[(size_t)g*QS + t];
  __syncthreads();
  int j = jb*256 + t;
  const float4* w = (const float4*)(Wsp + (size_t)j*QS);
  const float4* q4 = (const float4*)q_s;
  float acc = bsp[j];
  #pragma unroll
  for (int k4 = 0; k4 < 64; ++k4){
    float4 wv = w[k4]; float4 qv = q4[k4];
    acc += qv.x*wv.x + qv.y*wv.y + qv.z*wv.z + qv.w*wv.w;
  }
  float pw = prelu[0];
  out[(size_t)g*READOUT + j] = (acc >= 0.0f) ? acc : pw*acc;
}

extern "C" void kernel_launch(void* const* d_in, const int* in_sizes, int n_in,
                              void* d_out, int out_size, void* d_ws, size_t ws_size,
                              hipStream_t stream) {
  const float* node_feats = (const float*)d_in[0];
  const float* edge_feats = (const float*)d_in[1];
  const int*   esrc       = (const int*)d_in[2];
  const int*   edst       = (const int*)d_in[3];
  const float* Wproj = (const float*)d_in[5];
  const float* bproj = (const float*)d_in[6];
  const float* Wedge = (const float*)d_in[7];
  const float* bedge = (const float*)d_in[8];
  const float* bconv = (const float*)d_in[9];
  const float* gWih  = (const float*)d_in[10];
  const float* gWhh  = (const float*)d_in[11];
  const float* gbih  = (const float*)d_in[12];
  const float* gbhh  = (const float*)d_in[13];
  const float* lWih  = (const float*)d_in[14];
  const float* lWhh  = (const float*)d_in[15];
  const float* lbih  = (const float*)d_in[16];
  const float* lbhh  = (const float*)d_in[17];
  const float* Wsp   = (const float*)d_in[18];
  const float* bsp   = (const float*)d_in[19];
  const float* prelu = (const float*)d_in[20];

  float* ws    = (float*)d_ws;
  float* x0    = ws;                     // 2,560,000
  float* h     = ws + 2560000;           // 2,560,000
  float* agg   = ws + 5120000;           // 2,560,000
  float* qstar = ws + 7680000;           // 65,536
  float* hl    = qstar + 65536;          // 32,768
  float* cl    = hl + 32768;             // 32,768
  float* Bl2   = agg;                    // s2s phase reuses dead agg (196,608)

  hipMemsetAsync(qstar, 0, (65536 + 32768 + 32768)*sizeof(float), stream);

  pack_we3T<<<272, 256, 0, stream>>>(Wedge, bedge);
  pack_bcT<<<128, 256, 0, stream>>>(gWih, gWhh);

  proj_mm<<<N_NODES/64, 256, 0, stream>>>(node_feats, Wproj, bproj, x0, h);

  for (int s = 0; s < 3; ++s){
    if (s == 0)
      zero_buf<<<2048, 256, 0, stream>>>((float4*)agg, N_NODES*H/4);
    edge_mfma<<<N_EDGES/64, 256, 0, stream>>>(h, edge_feats, esrc, edst, agg);
    gru_mm_mfma<<<N_NODES/64, 256, 0, stream>>>(agg, bconv, h, gbih, gbhh);  // zeroes agg
  }

  build_bl2<<<768, 256, 0, stream>>>(lWih, lWhh, Bl2);

  for (int s = 0; s < 3; ++s){
    s2s_kernel<<<N_GRAPHS, 512, 0, stream>>>(x0, h, Bl2, lbih, lbhh, hl, cl, qstar);
  }

  out_kernel<<<4*N_GRAPHS, 256, 0, stream>>>(qstar, Wsp, bsp, prelu, (float*)d_out);
}

// Round 16
// 355.670 us; speedup vs baseline: 1.1728x; 1.0856x over previous
//
#include <hip/hip_runtime.h>
#include <math.h>

#define H 64
#define NODE_IN 128
#define EDGE_IN 16
#define N_NODES 40000
#define N_EDGES 80000
#define N_GRAPHS 256
#define READOUT 1024
#define D2 128   // 2H
#define QS 256   // 4H

typedef unsigned short u16;
typedef __attribute__((ext_vector_type(8))) short bf16x8;
typedef __attribute__((ext_vector_type(4))) float f32x4;
#define MFMA16(a,b,c) __builtin_amdgcn_mfma_f32_16x16x32_bf16(a,b,c,0,0,0)

// split-bf16 device globals
__device__ u16 d_xhi[N_NODES*H];
__device__ u16 d_xlo[N_NODES*H];
// [o][c] layout, bf16-RNE single stream (rel err 2^-9; covered by threshold headroom)
__device__ u16 d_we3T_hi[64*1088];
__device__ u16 d_bcT_hi[256*128];
__device__ u16 d_bcT_lo[256*128];

__device__ __forceinline__ float sigmoidf_(float x){ return 1.0f/(1.0f + expf(-x)); }

__device__ __forceinline__ u16 bf_hi(float x){
  union { float f; unsigned u; } c; c.f = x;
  unsigned r = (c.u + 0x7FFFu + ((c.u >> 16) & 1u)) >> 16;
  return (u16)r;
}
__device__ __forceinline__ float bf_f(u16 h){
  union { unsigned u; float f; } c; c.u = ((unsigned)h) << 16; return c.f;
}
__device__ __forceinline__ u16 bf_lo(float x, u16 hi){ return bf_hi(x - bf_f(hi)); }

// XOR-swizzled byte offset for [row][64 u16] tiles (128-B rows).
__device__ __forceinline__ int swz(int row, int kq){   // kq = bf16x8 group (0..7)
  return (row*128 + kq*16) ^ ((row & 7) << 4);
}

// trunc-split 8 f32 -> hi/lo bf16x8
__device__ __forceinline__ void split8(const float* Z, bf16x8& hv, bf16x8& lv){
  union { bf16x8 v; u16 u[8]; } hh, ll;
  #pragma unroll
  for (int k = 0; k < 8; ++k){
    union { float f; unsigned u; } cz; cz.f = Z[k];
    hh.u[k] = (u16)(cz.u >> 16);
    union { unsigned u; float f; } hf; hf.u = cz.u & 0xFFFF0000u;
    union { float f; unsigned u; } rz; rz.f = Z[k] - hf.f;
    ll.u[k] = (u16)(rz.u >> 16);
  }
  hv = hh.v; lv = ll.v;
}

// ==================== weight packs (once per launch) ====================
__global__ __launch_bounds__(256) void pack_we3T(
    const float* __restrict__ We, const float* __restrict__ be){
  int i = blockIdx.x*256 + threadIdx.x;     // 69632 = 64*1088
  int o = i / 1088, c = i % 1088;
  float v;
  if (c < 1024){
    int hh = c >> 4, k = c & 15;
    v = We[(size_t)(hh*64 + o)*EDGE_IN + k];
  } else {
    v = be[(size_t)(c - 1024)*64 + o];
  }
  d_we3T_hi[i] = bf_hi(v);   // RNE round; no lo stream
}

__global__ __launch_bounds__(256) void pack_bcT(
    const float* __restrict__ Wih, const float* __restrict__ Whh){
  int i = blockIdx.x*256 + threadIdx.x;     // 32768
  int k = i >> 8, c = i & 255;
  float v;
  if (c < 128){
    v = (k < 64) ? Wih[(size_t)c*H + k] : Whh[(size_t)c*H + (k-64)];
  } else if (c < 192){
    int d = c - 128;
    v = (k < 64) ? Wih[(size_t)(128+d)*H + k] : 0.f;
  } else {
    int d = c - 192;
    v = (k < 64) ? 0.f : Whh[(size_t)(128+d)*H + (k-64)];
  }
  u16 hi = bf_hi(v);
  d_bcT_hi[c*128 + k] = hi;
  d_bcT_lo[c*128 + k] = bf_lo(v, hi);
}

// ==================== zero fill ====================
__global__ __launch_bounds__(256) void zero_buf(float4* __restrict__ p, int n4){
  int i = blockIdx.x*256 + threadIdx.x;
  int stride = gridDim.x*256;
  for (; i < n4; i += stride) p[i] = make_float4(0.f,0.f,0.f,0.f);
}

// ==================== proj GEMM ====================
__global__ __launch_bounds__(256) void proj_mm(
    const float* __restrict__ nf, const float* __restrict__ Wp,
    const float* __restrict__ bp, float* __restrict__ x0, float* __restrict__ h){
  __shared__ float A_s[NODE_IN][64];
  __shared__ float B_s[NODE_IN][64];
  int t = threadIdx.x;
  int nb = blockIdx.x * 64;
  #pragma unroll
  for (int p = 0; p < 8; ++p){
    int idx = p*256 + t;
    int n = idx >> 5, k4 = idx & 31;
    float4 v = ((const float4*)(nf + (size_t)(nb+n)*NODE_IN))[k4];
    int base = (((n>>2) ^ (k4 & 15)) << 2) + (n & 3);
    A_s[k4*4+0][base]=v.x; A_s[k4*4+1][base]=v.y;
    A_s[k4*4+2][base]=v.z; A_s[k4*4+3][base]=v.w;
  }
  #pragma unroll
  for (int p = 0; p < 8; ++p){
    int idx = p*256 + t;
    int c = idx & 63, k4 = idx >> 6;
    float4 v = ((const float4*)(Wp + (size_t)c*NODE_IN))[k4];
    B_s[k4*4+0][c]=v.x; B_s[k4*4+1][c]=v.y; B_s[k4*4+2][c]=v.z; B_s[k4*4+3][c]=v.w;
  }
  __syncthreads();
  int eg = t & 15, cg = t >> 4;
  float acc[4][4] = {};
  #pragma unroll 4
  for (int k = 0; k < NODE_IN; ++k){
    int s = (k >> 2) & 15;
    float4 a = *(const float4*)&A_s[k][(eg ^ s) << 2];
    float4 b = *(const float4*)&B_s[k][cg*4];
    float av[4] = {a.x,a.y,a.z,a.w};
    float bv[4] = {b.x,b.y,b.z,b.w};
    #pragma unroll
    for (int j = 0; j < 4; ++j)
      #pragma unroll
      for (int c = 0; c < 4; ++c) acc[j][c] += av[j]*bv[c];
  }
  float4 bb = ((const float4*)bp)[cg];
  float bv[4] = {bb.x,bb.y,bb.z,bb.w};
  #pragma unroll
  for (int j = 0; j < 4; ++j){
    int n = nb + eg*4 + j;
    float o[4];
    #pragma unroll
    for (int c = 0; c < 4; ++c) o[c] = fmaxf(acc[j][c]+bv[c], 0.f);
    *(float4*)(x0 + (size_t)n*H + cg*4) = make_float4(o[0],o[1],o[2],o[3]);
    *(float4*)(h  + (size_t)n*H + cg*4) = make_float4(o[0],o[1],o[2],o[3]);
    u16 hs[4], ls[4];
    #pragma unroll
    for (int c = 0; c < 4; ++c){ hs[c] = bf_hi(o[c]); ls[c] = bf_lo(o[c], hs[c]); }
    *(ushort4*)&d_xhi[(size_t)n*H + cg*4] = make_ushort4(hs[0],hs[1],hs[2],hs[3]);
    *(ushort4*)&d_xlo[(size_t)n*H + cg*4] = make_ushort4(ls[0],ls[1],ls[2],ls[3]);
  }
}

// ==================== fused edge message (B single-stream bf16) ====
// msg[e][o] = Z_aug[e] @ B3[:,o]; A hi+lo (data), B bf16-RNE (weights).
// 4 MFMA per nt per chunk; B dbuf 2x8KB; LDS ~34 KB -> 4 blocks/CU.
__global__ __launch_bounds__(256) void edge_mfma(
    const float* __restrict__ xf, const float* __restrict__ ef,
    const int* __restrict__ src, const int* __restrict__ dst,
    float* __restrict__ agg){
  __shared__ __align__(16) char smem[16384];   // B dbuf: 2 x 8K
  __shared__ __align__(16) float x_s[64][68];  // 17.4 KB; msg overlay at flush
  __shared__ int src_s[64], dst_s[64];
  float* msg_s = (float*)x_s;

  int t = threadIdx.x;
  int w = t >> 6, lane = t & 63;
  int m = lane & 15, kq = lane >> 4;
  int ebase = blockIdx.x * 64;
  int e0 = t >> 2, j4 = t & 3;
  if (t < 64){ src_s[t] = src[ebase + t]; dst_s[t] = dst[ebase + t]; }
  { // stage B chunk 0 -> buf0
    const u16* gh = d_we3T_hi + (size_t)e0*1088 + j4*16;
    int b0 = swz(e0, 2*j4), b1 = swz(e0, 2*j4+1);
    *(bf16x8*)(smem + b0) = *(const bf16x8*)gh;
    *(bf16x8*)(smem + b1) = *(const bf16x8*)(gh+8);
  }
  __syncthreads();
  { // stage x rows
    const float4* px = (const float4*)(xf + (size_t)src_s[e0]*H + j4*16);
    float4 v0=px[0], v1=px[1], v2=px[2], v3=px[3];
    float* xr = &x_s[e0][j4*16];
    *(float4*)xr      = v0;
    *(float4*)(xr+4)  = v1;
    *(float4*)(xr+8)  = v2;
    *(float4*)(xr+12) = v3;
  }
  int e = w*16 + m;
  float ef8[8];
  {
    const float4* p = (const float4*)(ef + (size_t)(ebase+e)*EDGE_IN + (kq&1)*8);
    float4 a = p[0], b = p[1];
    ef8[0]=a.x; ef8[1]=a.y; ef8[2]=a.z; ef8[3]=a.w;
    ef8[4]=b.x; ef8[5]=b.y; ef8[6]=b.z; ef8[7]=b.w;
  }
  __syncthreads();

  int hsel = kq >> 1;
  f32x4 acc[4];
  #pragma unroll
  for (int i = 0; i < 4; ++i) acc[i] = (f32x4){0.f,0.f,0.f,0.f};

  #pragma unroll 2
  for (int ci = 0; ci < 16; ++ci){
    bf16x8 pbh0, pbh1;
    {
      const u16* gh = d_we3T_hi + (size_t)e0*1088 + (ci+1)*64 + j4*16;
      pbh0 = *(const bf16x8*)gh; pbh1 = *(const bf16x8*)(gh+8);
    }
    float x0v = x_s[e][ci*4 + hsel];
    float x1v = x_s[e][ci*4 + 2 + hsel];
    float Z0[8], Z1[8];
    #pragma unroll
    for (int j = 0; j < 8; ++j){ Z0[j] = x0v*ef8[j]; Z1[j] = x1v*ef8[j]; }
    bf16x8 ah0, al0, ah1, al1;
    split8(Z0, ah0, al0);
    split8(Z1, ah1, al1);
    {
      char* BhC = smem + (ci & 1)*8192;
      #pragma unroll
      for (int nt = 0; nt < 4; ++nt){
        int rb = nt*16 + m;
        int c0 = swz(rb, kq), c1 = c0 ^ 64;
        bf16x8 bh0 = *(const bf16x8*)(BhC + c0);
        bf16x8 bh1 = *(const bf16x8*)(BhC + c1);
        acc[nt] = MFMA16(ah0, bh0, acc[nt]);
        acc[nt] = MFMA16(ah1, bh1, acc[nt]);
        acc[nt] = MFMA16(al0, bh0, acc[nt]);
        acc[nt] = MFMA16(al1, bh1, acc[nt]);
      }
    }
    {
      char* BhN = smem + ((ci+1) & 1)*8192;
      int b0 = swz(e0, 2*j4), b1 = swz(e0, 2*j4+1);
      *(bf16x8*)(BhN + b0) = pbh0;
      *(bf16x8*)(BhN + b1) = pbh1;
    }
    __syncthreads();
  }
  { // bias chunk (ci=16) lands in buf0
    float xb[16];
    {
      const float4* q0 = (const float4*)&x_s[e][kq*8];
      const float4* q1 = (const float4*)&x_s[e][32 + kq*8];
      float4 a=q0[0], b=q0[1], c=q1[0], d=q1[1];
      xb[0]=a.x; xb[1]=a.y; xb[2]=a.z; xb[3]=a.w;
      xb[4]=b.x; xb[5]=b.y; xb[6]=b.z; xb[7]=b.w;
      xb[8]=c.x; xb[9]=c.y; xb[10]=c.z; xb[11]=c.w;
      xb[12]=d.x; xb[13]=d.y; xb[14]=d.z; xb[15]=d.w;
    }
    bf16x8 ah0, al0, ah1, al1;
    split8(xb,     ah0, al0);
    split8(xb + 8, ah1, al1);
    char* BhC = smem;
    #pragma unroll
    for (int nt = 0; nt < 4; ++nt){
      int rb = nt*16 + m;
      int c0 = swz(rb, kq), c1 = c0 ^ 64;
      bf16x8 bh0 = *(const bf16x8*)(BhC + c0);
      bf16x8 bh1 = *(const bf16x8*)(BhC + c1);
      acc[nt] = MFMA16(ah0, bh0, acc[nt]);
      acc[nt] = MFMA16(ah1, bh1, acc[nt]);
      acc[nt] = MFMA16(al0, bh0, acc[nt]);
      acc[nt] = MFMA16(al1, bh1, acc[nt]);
    }
  }
  __syncthreads();
  #pragma unroll
  for (int nt = 0; nt < 4; ++nt){
    int o = nt*16 + m;
    #pragma unroll
    for (int r = 0; r < 4; ++r){
      int ee = w*16 + kq*4 + r;
      msg_s[ee*64 + (o ^ ((ee & 7) << 2))] = acc[nt][r];
    }
  }
  __syncthreads();
  #pragma unroll
  for (int r = 0; r < 16; ++r){
    int ee = w*16 + r;
    atomicAdd(&agg[(size_t)dst_s[ee]*H + lane],
              msg_s[ee*64 + (lane ^ ((ee & 7) << 2))]);
  }
}

// ==================== GRU GEMM + fused epilogue; B chunk reg-prefetched ====
__global__ __launch_bounds__(256) void gru_mm_mfma(
    float* __restrict__ agg, const float* __restrict__ bconv,
    float* __restrict__ h, const float* __restrict__ gbih,
    const float* __restrict__ gbhh){
  __shared__ u16 Ah[64][40], Al[64][40];
  __shared__ u16 Bh[256][40], Bl_[256][40];
  __shared__ float bih_s[192], bhh_s[192];
  int t = threadIdx.x;
  int w = t >> 6, lane = t & 63;
  int nb = blockIdx.x * 64;
  if (t < 192){ bih_s[t] = gbih[t]; bhh_s[t] = gbhh[t]; }
  int m = lane & 15, kj = (lane >> 4) * 8;
  f32x4 acc[16];
  #pragma unroll
  for (int i = 0; i < 16; ++i) acc[i] = (f32x4){0.f,0.f,0.f,0.f};
  bf16x8 pbh[4], pbl[4];
  #pragma unroll
  for (int qq = 0; qq < 4; ++qq){
    int gofs = t*128 + qq*8;
    pbh[qq] = *(const bf16x8*)&d_bcT_hi[gofs];
    pbl[qq] = *(const bf16x8*)&d_bcT_lo[gofs];
  }
  for (int kc = 0; kc < 4; ++kc){
    __syncthreads();
    {
      int n = t >> 2, q = t & 3;
      if (kc < 2){
        float* sp = agg + (size_t)(nb+n)*H + kc*32 + q*8;
        float4 v0 = *(const float4*)sp;
        float4 v1 = *(const float4*)(sp + 4);
        float4 b0 = *(const float4*)&bconv[kc*32 + q*8];
        float4 b1 = *(const float4*)&bconv[kc*32 + q*8 + 4];
        *(float4*)sp       = make_float4(0.f,0.f,0.f,0.f);
        *(float4*)(sp + 4) = make_float4(0.f,0.f,0.f,0.f);
        float vals[8] = { fmaxf(v0.x+b0.x,0.f), fmaxf(v0.y+b0.y,0.f),
                          fmaxf(v0.z+b0.z,0.f), fmaxf(v0.w+b0.w,0.f),
                          fmaxf(v1.x+b1.x,0.f), fmaxf(v1.y+b1.y,0.f),
                          fmaxf(v1.z+b1.z,0.f), fmaxf(v1.w+b1.w,0.f) };
        union { bf16x8 v; u16 u[8]; } ph, pl;
        #pragma unroll
        for (int j = 0; j < 8; ++j){
          u16 hi = bf_hi(vals[j]);
          ph.u[j] = hi; pl.u[j] = bf_lo(vals[j], hi);
        }
        *(bf16x8*)&Ah[n][q*8] = ph.v;
        *(bf16x8*)&Al[n][q*8] = pl.v;
      } else {
        int gofs = (nb+n)*H + (kc-2)*32 + q*8;
        *(bf16x8*)&Ah[n][q*8] = *(const bf16x8*)&d_xhi[gofs];
        *(bf16x8*)&Al[n][q*8] = *(const bf16x8*)&d_xlo[gofs];
      }
    }
    #pragma unroll
    for (int qq = 0; qq < 4; ++qq){
      *(bf16x8*)&Bh[t][qq*8]  = pbh[qq];
      *(bf16x8*)&Bl_[t][qq*8] = pbl[qq];
    }
    if (kc < 3){
      #pragma unroll
      for (int qq = 0; qq < 4; ++qq){
        int gofs = t*128 + (kc+1)*32 + qq*8;
        pbh[qq] = *(const bf16x8*)&d_bcT_hi[gofs];
        pbl[qq] = *(const bf16x8*)&d_bcT_lo[gofs];
      }
    }
    __syncthreads();
    bf16x8 ah = *(const bf16x8*)&Ah[w*16 + m][kj];
    bf16x8 al = *(const bf16x8*)&Al[w*16 + m][kj];
    #pragma unroll
    for (int nt = 0; nt < 16; ++nt){
      bf16x8 bh = *(const bf16x8*)&Bh[nt*16 + m][kj];
      bf16x8 bl = *(const bf16x8*)&Bl_[nt*16 + m][kj];
      acc[nt] = MFMA16(ah, bh, acc[nt]);
      acc[nt] = MFMA16(ah, bl, acc[nt]);
      acc[nt] = MFMA16(al, bh, acc[nt]);
    }
  }
  int q4 = lane >> 4, col0 = lane & 15;
  #pragma unroll
  for (int r = 0; r < 4; ++r){
    int node = nb + w*16 + q4*4 + r;
    #pragma unroll
    for (int j = 0; j < 4; ++j){
      int d = col0 + 16*j;
      float rg = sigmoidf_(acc[j][r]   + bih_s[d]      + bhh_s[d]);
      float z  = sigmoidf_(acc[4+j][r] + bih_s[64+d]   + bhh_s[64+d]);
      float nn = tanhf(acc[8+j][r] + bih_s[128+d] + rg*(acc[12+j][r] + bhh_s[128+d]));
      size_t off = (size_t)node*H + d;
      float hv = h[off];
      float hn = (1.f - z)*nn + z*hv;
      h[off] = hn;
      u16 hb = bf_hi(hn);
      d_xhi[off] = hb;
      d_xlo[off] = bf_lo(hn, hb);
    }
  }
}

// ==================== Bl2 pack ====================
__global__ __launch_bounds__(256) void build_bl2(
    const float* __restrict__ Wih, const float* __restrict__ Whh,
    float* __restrict__ Bl2){
  int i = blockIdx.x*256 + threadIdx.x;   // 196608
  int k = i >> 9, c = i & 511;
  int d = c >> 2, gate = c & 3;
  int row = gate*128 + d;
  float v = (k < 256) ? Wih[(size_t)row*QS + k] : Whh[(size_t)row*D2 + (k-256)];
  Bl2[i] = v;
}

// ==================== fused Set2Set step: LSTM cell + attention (512 thr) ====
__global__ __launch_bounds__(512) void s2s_kernel(
    const float* __restrict__ x0, const float* __restrict__ h,
    const float* __restrict__ Bl2, const float* __restrict__ lbih,
    const float* __restrict__ lbhh, float* __restrict__ hl,
    float* __restrict__ cl, float* __restrict__ qstar){
  __shared__ float A_s[384];
  __shared__ float part4[4][128][4];
  __shared__ float q_s[D2];
  __shared__ float alpha_s[160];
  __shared__ float wred[8];
  __shared__ float part[8][D2];
  int g = blockIdx.x, t = threadIdx.x;
  int lane = t & 63, w = t >> 6;
  if (t < 384){
    A_s[t] = (t < 256) ? qstar[(size_t)g*QS + t] : hl[(size_t)g*D2 + (t - 256)];
  }
  __syncthreads();
  {
    int d = t & 127, ks = t >> 7;
    const float* bp = Bl2 + 4*d;
    float ai = 0.f, af = 0.f, ag = 0.f, ao = 0.f;
    #pragma unroll 8
    for (int kk = 0; kk < 96; ++kk){
      int k = ks*96 + kk;
      float a = A_s[k];
      float4 b = *(const float4*)(bp + (size_t)k*512);
      ai += a*b.x; af += a*b.y; ag += a*b.z; ao += a*b.w;
    }
    *(float4*)&part4[ks][d][0] = make_float4(ai, af, ag, ao);
  }
  __syncthreads();
  if (t < D2){
    float4 p0 = *(const float4*)&part4[0][t][0];
    float4 p1 = *(const float4*)&part4[1][t][0];
    float4 p2 = *(const float4*)&part4[2][t][0];
    float4 p3 = *(const float4*)&part4[3][t][0];
    float iv = p0.x+p1.x+p2.x+p3.x + lbih[t]       + lbhh[t];
    float fv = p0.y+p1.y+p2.y+p3.y + lbih[128 + t] + lbhh[128 + t];
    float gv = p0.z+p1.z+p2.z+p3.z + lbih[256 + t] + lbhh[256 + t];
    float ov = p0.w+p1.w+p2.w+p3.w + lbih[384 + t] + lbhh[384 + t];
    float c = sigmoidf_(fv)*cl[(size_t)g*D2 + t] + sigmoidf_(iv)*tanhf(gv);
    float hn = sigmoidf_(ov)*tanhf(c);
    cl[(size_t)g*D2 + t] = c;
    hl[(size_t)g*D2 + t] = hn;
    q_s[t] = hn;
  }
  __syncthreads();
  int n0 = (g*N_NODES + N_GRAPHS - 1)/N_GRAPHS;
  int n1 = ((g+1)*N_NODES + N_GRAPHS - 1)/N_GRAPHS;
  int cnt = n1 - n0;
  float e = -1e30f;
  if (t < cnt){
    int n = n0 + t;
    const float4* xr = (const float4*)(x0 + (size_t)n*H);
    const float4* hr = (const float4*)(h  + (size_t)n*H);
    const float4* q1 = (const float4*)q_s;
    const float4* q2 = (const float4*)(q_s + H);
    float s = 0.0f;
    #pragma unroll
    for (int k4 = 0; k4 < 16; ++k4){
      float4 a = xr[k4], b = q1[k4];
      s += a.x*b.x + a.y*b.y + a.z*b.z + a.w*b.w;
    }
    #pragma unroll
    for (int k4 = 0; k4 < 16; ++k4){
      float4 a = hr[k4], b = q2[k4];
      s += a.x*b.x + a.y*b.y + a.z*b.z + a.w*b.w;
    }
    e = s;
  }
  float mx = e;
  #pragma unroll
  for (int off = 32; off >= 1; off >>= 1) mx = fmaxf(mx, __shfl_xor(mx, off));
  if (lane == 0) wred[w] = mx;
  __syncthreads();
  float gm = wred[0];
  #pragma unroll
  for (int i = 1; i < 8; ++i) gm = fmaxf(gm, wred[i]);
  __syncthreads();
  float ex = (t < cnt) ? expf(e - gm) : 0.0f;
  float sm = ex;
  #pragma unroll
  for (int off = 32; off >= 1; off >>= 1) sm += __shfl_xor(sm, off);
  if (lane == 0) wred[w] = sm;
  __syncthreads();
  float denom = wred[0]+wred[1]+wred[2]+wred[3]+wred[4]+wred[5]+wred[6]+wred[7];
  if (t < cnt) alpha_s[t] = ex / denom;
  __syncthreads();
  float acc0 = 0.f, acc1 = 0.f;
  for (int i = w; i < cnt; i += 8){
    float a = alpha_s[i];
    acc0 += a * x0[(size_t)(n0+i)*H + lane];
    acc1 += a * h [(size_t)(n0+i)*H + lane];
  }
  part[w][lane]      = acc0;
  part[w][64 + lane] = acc1;
  __syncthreads();
  if (t < D2){
    float v = 0.f;
    #pragma unroll
    for (int i = 0; i < 8; ++i) v += part[i][t];
    qstar[(size_t)g*QS + t]      = q_s[t];
    qstar[(size_t)g*QS + D2 + t] = v;
  }
}

// ==================== readout ====================
__global__ __launch_bounds__(256) void out_kernel(
    const float* __restrict__ qstar, const float* __restrict__ Wsp,
    const float* __restrict__ bsp, const float* __restrict__ prelu,
    float* __restrict__ out){
  __shared__ float q_s[QS];
  int g = blockIdx.x & 255;
  int jb = blockIdx.x >> 8;
  int t = threadIdx.x;
  q_s[t] = qstar[(size_t)g*QS + t];
  __syncthreads();
  int j = jb*256 + t;
  const float4* w = (const float4*)(Wsp + (size_t)j*QS);
  const float4* q4 = (const float4*)q_s;
  float acc = bsp[j];
  #pragma unroll
  for (int k4 = 0; k4 < 64; ++k4){
    float4 wv = w[k4]; float4 qv = q4[k4];
    acc += qv.x*wv.x + qv.y*wv.y + qv.z*wv.z + qv.w*wv.w;
  }
  float pw = prelu[0];
  out[(size_t)g*READOUT + j] = (acc >= 0.0f) ? acc : pw*acc;
}

extern "C" void kernel_launch(void* const* d_in, const int* in_sizes, int n_in,
                              void* d_out, int out_size, void* d_ws, size_t ws_size,
                              hipStream_t stream) {
  const float* node_feats = (const float*)d_in[0];
  const float* edge_feats = (const float*)d_in[1];
  const int*   esrc       = (const int*)d_in[2];
  const int*   edst       = (const int*)d_in[3];
  const float* Wproj = (const float*)d_in[5];
  const float* bproj = (const float*)d_in[6];
  const float* Wedge = (const float*)d_in[7];
  const float* bedge = (const float*)d_in[8];
  const float* bconv = (const float*)d_in[9];
  const float* gWih  = (const float*)d_in[10];
  const float* gWhh  = (const float*)d_in[11];
  const float* gbih  = (const float*)d_in[12];
  const float* gbhh  = (const float*)d_in[13];
  const float* lWih  = (const float*)d_in[14];
  const float* lWhh  = (const float*)d_in[15];
  const float* lbih  = (const float*)d_in[16];
  const float* lbhh  = (const float*)d_in[17];
  const float* Wsp   = (const float*)d_in[18];
  const float* bsp   = (const float*)d_in[19];
  const float* prelu = (const float*)d_in[20];

  float* ws    = (float*)d_ws;
  float* x0    = ws;                     // 2,560,000
  float* h     = ws + 2560000;           // 2,560,000
  float* agg   = ws + 5120000;           // 2,560,000
  float* qstar = ws + 7680000;           // 65,536
  float* hl    = qstar + 65536;          // 32,768
  float* cl    = hl + 32768;             // 32,768
  float* Bl2   = agg;                    // s2s phase reuses dead agg (196,608)

  hipMemsetAsync(qstar, 0, (65536 + 32768 + 32768)*sizeof(float), stream);

  pack_we3T<<<272, 256, 0, stream>>>(Wedge, bedge);
  pack_bcT<<<128, 256, 0, stream>>>(gWih, gWhh);

  proj_mm<<<N_NODES/64, 256, 0, stream>>>(node_feats, Wproj, bproj, x0, h);

  for (int s = 0; s < 3; ++s){
    if (s == 0)
      zero_buf<<<2048, 256, 0, stream>>>((float4*)agg, N_NODES*H/4);
    edge_mfma<<<N_EDGES/64, 256, 0, stream>>>(h, edge_feats, esrc, edst, agg);
    gru_mm_mfma<<<N_NODES/64, 256, 0, stream>>>(agg, bconv, h, gbih, gbhh);  // zeroes agg
  }

  build_bl2<<<768, 256, 0, stream>>>(lWih, lWhh, Bl2);

  for (int s = 0; s < 3; ++s){
    s2s_kernel<<<N_GRAPHS, 512, 0, stream>>>(x0, h, Bl2, lbih, lbhh, hl, cl, qstar);
  }

  out_kernel<<<4*N_GRAPHS, 256, 0, stream>>>(qstar, Wsp, bsp, prelu, (float*)d_out);
}

// Round 17
// 325.647 us; speedup vs baseline: 1.2809x; 1.0922x over previous
//
#include <hip/hip_runtime.h>
#include <math.h>

#define H 64
#define NODE_IN 128
#define EDGE_IN 16
#define N_NODES 40000
#define N_EDGES 80000
#define N_GRAPHS 256
#define READOUT 1024
#define D2 128   // 2H
#define QS 256   // 4H

typedef unsigned short u16;
typedef __attribute__((ext_vector_type(8))) short bf16x8;
typedef __attribute__((ext_vector_type(4))) float f32x4;
#define MFMA16(a,b,c) __builtin_amdgcn_mfma_f32_16x16x32_bf16(a,b,c,0,0,0)

// split-bf16 device globals (A/state path keeps hi+lo; weights single bf16-RNE)
__device__ u16 d_xhi[N_NODES*H];
__device__ u16 d_xlo[N_NODES*H];
__device__ u16 d_we3T_hi[64*1088];   // [o][c] bf16-RNE
__device__ u16 d_bcT_hi[256*128];    // bf16-RNE (lo dropped round 17)

__device__ __forceinline__ float sigmoidf_(float x){ return 1.0f/(1.0f + expf(-x)); }

__device__ __forceinline__ u16 bf_hi(float x){
  union { float f; unsigned u; } c; c.f = x;
  unsigned r = (c.u + 0x7FFFu + ((c.u >> 16) & 1u)) >> 16;
  return (u16)r;
}
__device__ __forceinline__ float bf_f(u16 h){
  union { unsigned u; float f; } c; c.u = ((unsigned)h) << 16; return c.f;
}
__device__ __forceinline__ u16 bf_lo(float x, u16 hi){ return bf_hi(x - bf_f(hi)); }

// XOR-swizzled byte offset for [row][64 u16] tiles (128-B rows).
__device__ __forceinline__ int swz(int row, int kq){   // kq = bf16x8 group (0..7)
  return (row*128 + kq*16) ^ ((row & 7) << 4);
}

// RNE-round 8 f32 -> bf16x8 (single stream)
__device__ __forceinline__ bf16x8 rne8(const float* Z){
  union { bf16x8 v; u16 u[8]; } hh;
  #pragma unroll
  for (int k = 0; k < 8; ++k) hh.u[k] = bf_hi(Z[k]);
  return hh.v;
}

// ==================== weight packs (once per launch) ====================
__global__ __launch_bounds__(256) void pack_we3T(
    const float* __restrict__ We, const float* __restrict__ be){
  int i = blockIdx.x*256 + threadIdx.x;     // 69632 = 64*1088
  int o = i / 1088, c = i % 1088;
  float v;
  if (c < 1024){
    int hh = c >> 4, k = c & 15;
    v = We[(size_t)(hh*64 + o)*EDGE_IN + k];
  } else {
    v = be[(size_t)(c - 1024)*64 + o];
  }
  d_we3T_hi[i] = bf_hi(v);
}

__global__ __launch_bounds__(256) void pack_bcT(
    const float* __restrict__ Wih, const float* __restrict__ Whh){
  int i = blockIdx.x*256 + threadIdx.x;     // 32768
  int k = i >> 8, c = i & 255;
  float v;
  if (c < 128){
    v = (k < 64) ? Wih[(size_t)c*H + k] : Whh[(size_t)c*H + (k-64)];
  } else if (c < 192){
    int d = c - 128;
    v = (k < 64) ? Wih[(size_t)(128+d)*H + k] : 0.f;
  } else {
    int d = c - 192;
    v = (k < 64) ? 0.f : Whh[(size_t)(128+d)*H + (k-64)];
  }
  d_bcT_hi[c*128 + k] = bf_hi(v);
}

// ==================== zero fill ====================
__global__ __launch_bounds__(256) void zero_buf(float4* __restrict__ p, int n4){
  int i = blockIdx.x*256 + threadIdx.x;
  int stride = gridDim.x*256;
  for (; i < n4; i += stride) p[i] = make_float4(0.f,0.f,0.f,0.f);
}

// ==================== proj GEMM ====================
__global__ __launch_bounds__(256) void proj_mm(
    const float* __restrict__ nf, const float* __restrict__ Wp,
    const float* __restrict__ bp, float* __restrict__ x0, float* __restrict__ h){
  __shared__ float A_s[NODE_IN][64];
  __shared__ float B_s[NODE_IN][64];
  int t = threadIdx.x;
  int nb = blockIdx.x * 64;
  #pragma unroll
  for (int p = 0; p < 8; ++p){
    int idx = p*256 + t;
    int n = idx >> 5, k4 = idx & 31;
    float4 v = ((const float4*)(nf + (size_t)(nb+n)*NODE_IN))[k4];
    int base = (((n>>2) ^ (k4 & 15)) << 2) + (n & 3);
    A_s[k4*4+0][base]=v.x; A_s[k4*4+1][base]=v.y;
    A_s[k4*4+2][base]=v.z; A_s[k4*4+3][base]=v.w;
  }
  #pragma unroll
  for (int p = 0; p < 8; ++p){
    int idx = p*256 + t;
    int c = idx & 63, k4 = idx >> 6;
    float4 v = ((const float4*)(Wp + (size_t)c*NODE_IN))[k4];
    B_s[k4*4+0][c]=v.x; B_s[k4*4+1][c]=v.y; B_s[k4*4+2][c]=v.z; B_s[k4*4+3][c]=v.w;
  }
  __syncthreads();
  int eg = t & 15, cg = t >> 4;
  float acc[4][4] = {};
  #pragma unroll 4
  for (int k = 0; k < NODE_IN; ++k){
    int s = (k >> 2) & 15;
    float4 a = *(const float4*)&A_s[k][(eg ^ s) << 2];
    float4 b = *(const float4*)&B_s[k][cg*4];
    float av[4] = {a.x,a.y,a.z,a.w};
    float bv[4] = {b.x,b.y,b.z,b.w};
    #pragma unroll
    for (int j = 0; j < 4; ++j)
      #pragma unroll
      for (int c = 0; c < 4; ++c) acc[j][c] += av[j]*bv[c];
  }
  float4 bb = ((const float4*)bp)[cg];
  float bv[4] = {bb.x,bb.y,bb.z,bb.w};
  #pragma unroll
  for (int j = 0; j < 4; ++j){
    int n = nb + eg*4 + j;
    float o[4];
    #pragma unroll
    for (int c = 0; c < 4; ++c) o[c] = fmaxf(acc[j][c]+bv[c], 0.f);
    *(float4*)(x0 + (size_t)n*H + cg*4) = make_float4(o[0],o[1],o[2],o[3]);
    *(float4*)(h  + (size_t)n*H + cg*4) = make_float4(o[0],o[1],o[2],o[3]);
    u16 hs[4], ls[4];
    #pragma unroll
    for (int c = 0; c < 4; ++c){ hs[c] = bf_hi(o[c]); ls[c] = bf_lo(o[c], hs[c]); }
    *(ushort4*)&d_xhi[(size_t)n*H + cg*4] = make_ushort4(hs[0],hs[1],hs[2],hs[3]);
    *(ushort4*)&d_xlo[(size_t)n*H + cg*4] = make_ushort4(ls[0],ls[1],ls[2],ls[3]);
  }
}

// ==================== fused edge message (A and B single-stream bf16) ====
// msg[e][o] = Z_aug[e] @ B3[:,o]; Z rounded RNE (rel 2^-9, inside threshold
// headroom). 2 MFMA per nt per chunk; B dbuf 2x8KB; LDS ~34 KB.
__global__ __launch_bounds__(256) void edge_mfma(
    const float* __restrict__ xf, const float* __restrict__ ef,
    const int* __restrict__ src, const int* __restrict__ dst,
    float* __restrict__ agg){
  __shared__ __align__(16) char smem[16384];   // B dbuf: 2 x 8K
  __shared__ __align__(16) float x_s[64][68];  // 17.4 KB; msg overlay at flush
  __shared__ int src_s[64], dst_s[64];
  float* msg_s = (float*)x_s;

  int t = threadIdx.x;
  int w = t >> 6, lane = t & 63;
  int m = lane & 15, kq = lane >> 4;
  int ebase = blockIdx.x * 64;
  int e0 = t >> 2, j4 = t & 3;
  if (t < 64){ src_s[t] = src[ebase + t]; dst_s[t] = dst[ebase + t]; }
  { // stage B chunk 0 -> buf0
    const u16* gh = d_we3T_hi + (size_t)e0*1088 + j4*16;
    int b0 = swz(e0, 2*j4), b1 = swz(e0, 2*j4+1);
    *(bf16x8*)(smem + b0) = *(const bf16x8*)gh;
    *(bf16x8*)(smem + b1) = *(const bf16x8*)(gh+8);
  }
  __syncthreads();
  { // stage x rows
    const float4* px = (const float4*)(xf + (size_t)src_s[e0]*H + j4*16);
    float4 v0=px[0], v1=px[1], v2=px[2], v3=px[3];
    float* xr = &x_s[e0][j4*16];
    *(float4*)xr      = v0;
    *(float4*)(xr+4)  = v1;
    *(float4*)(xr+8)  = v2;
    *(float4*)(xr+12) = v3;
  }
  int e = w*16 + m;
  float ef8[8];
  {
    const float4* p = (const float4*)(ef + (size_t)(ebase+e)*EDGE_IN + (kq&1)*8);
    float4 a = p[0], b = p[1];
    ef8[0]=a.x; ef8[1]=a.y; ef8[2]=a.z; ef8[3]=a.w;
    ef8[4]=b.x; ef8[5]=b.y; ef8[6]=b.z; ef8[7]=b.w;
  }
  __syncthreads();

  int hsel = kq >> 1;
  f32x4 acc[4];
  #pragma unroll
  for (int i = 0; i < 4; ++i) acc[i] = (f32x4){0.f,0.f,0.f,0.f};

  #pragma unroll 2
  for (int ci = 0; ci < 16; ++ci){
    bf16x8 pbh0, pbh1;
    {
      const u16* gh = d_we3T_hi + (size_t)e0*1088 + (ci+1)*64 + j4*16;
      pbh0 = *(const bf16x8*)gh; pbh1 = *(const bf16x8*)(gh+8);
    }
    float x0v = x_s[e][ci*4 + hsel];
    float x1v = x_s[e][ci*4 + 2 + hsel];
    float Z0[8], Z1[8];
    #pragma unroll
    for (int j = 0; j < 8; ++j){ Z0[j] = x0v*ef8[j]; Z1[j] = x1v*ef8[j]; }
    bf16x8 a0 = rne8(Z0), a1 = rne8(Z1);
    {
      char* BhC = smem + (ci & 1)*8192;
      #pragma unroll
      for (int nt = 0; nt < 4; ++nt){
        int rb = nt*16 + m;
        int c0 = swz(rb, kq), c1 = c0 ^ 64;
        bf16x8 bh0 = *(const bf16x8*)(BhC + c0);
        bf16x8 bh1 = *(const bf16x8*)(BhC + c1);
        acc[nt] = MFMA16(a0, bh0, acc[nt]);
        acc[nt] = MFMA16(a1, bh1, acc[nt]);
      }
    }
    {
      char* BhN = smem + ((ci+1) & 1)*8192;
      int b0 = swz(e0, 2*j4), b1 = swz(e0, 2*j4+1);
      *(bf16x8*)(BhN + b0) = pbh0;
      *(bf16x8*)(BhN + b1) = pbh1;
    }
    __syncthreads();
  }
  { // bias chunk (ci=16) lands in buf0
    float xb[16];
    {
      const float4* q0 = (const float4*)&x_s[e][kq*8];
      const float4* q1 = (const float4*)&x_s[e][32 + kq*8];
      float4 a=q0[0], b=q0[1], c=q1[0], d=q1[1];
      xb[0]=a.x; xb[1]=a.y; xb[2]=a.z; xb[3]=a.w;
      xb[4]=b.x; xb[5]=b.y; xb[6]=b.z; xb[7]=b.w;
      xb[8]=c.x; xb[9]=c.y; xb[10]=c.z; xb[11]=c.w;
      xb[12]=d.x; xb[13]=d.y; xb[14]=d.z; xb[15]=d.w;
    }
    bf16x8 a0 = rne8(xb), a1 = rne8(xb + 8);
    char* BhC = smem;
    #pragma unroll
    for (int nt = 0; nt < 4; ++nt){
      int rb = nt*16 + m;
      int c0 = swz(rb, kq), c1 = c0 ^ 64;
      bf16x8 bh0 = *(const bf16x8*)(BhC + c0);
      bf16x8 bh1 = *(const bf16x8*)(BhC + c1);
      acc[nt] = MFMA16(a0, bh0, acc[nt]);
      acc[nt] = MFMA16(a1, bh1, acc[nt]);
    }
  }
  __syncthreads();
  #pragma unroll
  for (int nt = 0; nt < 4; ++nt){
    int o = nt*16 + m;
    #pragma unroll
    for (int r = 0; r < 4; ++r){
      int ee = w*16 + kq*4 + r;
      msg_s[ee*64 + (o ^ ((ee & 7) << 2))] = acc[nt][r];
    }
  }
  __syncthreads();
  #pragma unroll
  for (int r = 0; r < 16; ++r){
    int ee = w*16 + r;
    atomicAdd(&agg[(size_t)dst_s[ee]*H + lane],
              msg_s[ee*64 + (lane ^ ((ee & 7) << 2))]);
  }
}

// ==================== GRU GEMM + fused epilogue (B single-stream bf16) ====
// A (relu(agg+b)|h) keeps hi+lo; B bf16-RNE. 2 MFMA per nt per chunk.
// LDS ~32 KB -> 4 blocks/CU. Zeroes agg rows after reading.
__global__ __launch_bounds__(256) void gru_mm_mfma(
    float* __restrict__ agg, const float* __restrict__ bconv,
    float* __restrict__ h, const float* __restrict__ gbih,
    const float* __restrict__ gbhh){
  __shared__ u16 Ah[64][40], Al[64][40];
  __shared__ u16 Bh[256][40];
  __shared__ float bih_s[192], bhh_s[192];
  int t = threadIdx.x;
  int w = t >> 6, lane = t & 63;
  int nb = blockIdx.x * 64;
  if (t < 192){ bih_s[t] = gbih[t]; bhh_s[t] = gbhh[t]; }
  int m = lane & 15, kj = (lane >> 4) * 8;
  f32x4 acc[16];
  #pragma unroll
  for (int i = 0; i < 16; ++i) acc[i] = (f32x4){0.f,0.f,0.f,0.f};
  bf16x8 pbh[4];
  #pragma unroll
  for (int qq = 0; qq < 4; ++qq)
    pbh[qq] = *(const bf16x8*)&d_bcT_hi[t*128 + qq*8];
  for (int kc = 0; kc < 4; ++kc){
    __syncthreads();
    {
      int n = t >> 2, q = t & 3;
      if (kc < 2){
        float* sp = agg + (size_t)(nb+n)*H + kc*32 + q*8;
        float4 v0 = *(const float4*)sp;
        float4 v1 = *(const float4*)(sp + 4);
        float4 b0 = *(const float4*)&bconv[kc*32 + q*8];
        float4 b1 = *(const float4*)&bconv[kc*32 + q*8 + 4];
        *(float4*)sp       = make_float4(0.f,0.f,0.f,0.f);
        *(float4*)(sp + 4) = make_float4(0.f,0.f,0.f,0.f);
        float vals[8] = { fmaxf(v0.x+b0.x,0.f), fmaxf(v0.y+b0.y,0.f),
                          fmaxf(v0.z+b0.z,0.f), fmaxf(v0.w+b0.w,0.f),
                          fmaxf(v1.x+b1.x,0.f), fmaxf(v1.y+b1.y,0.f),
                          fmaxf(v1.z+b1.z,0.f), fmaxf(v1.w+b1.w,0.f) };
        union { bf16x8 v; u16 u[8]; } ph, pl;
        #pragma unroll
        for (int j = 0; j < 8; ++j){
          u16 hi = bf_hi(vals[j]);
          ph.u[j] = hi; pl.u[j] = bf_lo(vals[j], hi);
        }
        *(bf16x8*)&Ah[n][q*8] = ph.v;
        *(bf16x8*)&Al[n][q*8] = pl.v;
      } else {
        int gofs = (nb+n)*H + (kc-2)*32 + q*8;
        *(bf16x8*)&Ah[n][q*8] = *(const bf16x8*)&d_xhi[gofs];
        *(bf16x8*)&Al[n][q*8] = *(const bf16x8*)&d_xlo[gofs];
      }
    }
    #pragma unroll
    for (int qq = 0; qq < 4; ++qq)
      *(bf16x8*)&Bh[t][qq*8] = pbh[qq];
    if (kc < 3){
      #pragma unroll
      for (int qq = 0; qq < 4; ++qq)
        pbh[qq] = *(const bf16x8*)&d_bcT_hi[t*128 + (kc+1)*32 + qq*8];
    }
    __syncthreads();
    bf16x8 ah = *(const bf16x8*)&Ah[w*16 + m][kj];
    bf16x8 al = *(const bf16x8*)&Al[w*16 + m][kj];
    #pragma unroll
    for (int nt = 0; nt < 16; ++nt){
      bf16x8 bh = *(const bf16x8*)&Bh[nt*16 + m][kj];
      acc[nt] = MFMA16(ah, bh, acc[nt]);
      acc[nt] = MFMA16(al, bh, acc[nt]);
    }
  }
  int q4 = lane >> 4, col0 = lane & 15;
  #pragma unroll
  for (int r = 0; r < 4; ++r){
    int node = nb + w*16 + q4*4 + r;
    #pragma unroll
    for (int j = 0; j < 4; ++j){
      int d = col0 + 16*j;
      float rg = sigmoidf_(acc[j][r]   + bih_s[d]      + bhh_s[d]);
      float z  = sigmoidf_(acc[4+j][r] + bih_s[64+d]   + bhh_s[64+d]);
      float nn = tanhf(acc[8+j][r] + bih_s[128+d] + rg*(acc[12+j][r] + bhh_s[128+d]));
      size_t off = (size_t)node*H + d;
      float hv = h[off];
      float hn = (1.f - z)*nn + z*hv;
      h[off] = hn;
      u16 hb = bf_hi(hn);
      d_xhi[off] = hb;
      d_xlo[off] = bf_lo(hn, hb);
    }
  }
}

// ==================== Bl2 pack ====================
__global__ __launch_bounds__(256) void build_bl2(
    const float* __restrict__ Wih, const float* __restrict__ Whh,
    float* __restrict__ Bl2){
  int i = blockIdx.x*256 + threadIdx.x;   // 196608
  int k = i >> 9, c = i & 511;
  int d = c >> 2, gate = c & 3;
  int row = gate*128 + d;
  float v = (k < 256) ? Wih[(size_t)row*QS + k] : Whh[(size_t)row*D2 + (k-256)];
  Bl2[i] = v;
}

// ==================== fused Set2Set step: LSTM cell + attention (512 thr) ====
__global__ __launch_bounds__(512) void s2s_kernel(
    const float* __restrict__ x0, const float* __restrict__ h,
    const float* __restrict__ Bl2, const float* __restrict__ lbih,
    const float* __restrict__ lbhh, float* __restrict__ hl,
    float* __restrict__ cl, float* __restrict__ qstar){
  __shared__ float A_s[384];
  __shared__ float part4[4][128][4];
  __shared__ float q_s[D2];
  __shared__ float alpha_s[160];
  __shared__ float wred[8];
  __shared__ float part[8][D2];
  int g = blockIdx.x, t = threadIdx.x;
  int lane = t & 63, w = t >> 6;
  if (t < 384){
    A_s[t] = (t < 256) ? qstar[(size_t)g*QS + t] : hl[(size_t)g*D2 + (t - 256)];
  }
  __syncthreads();
  {
    int d = t & 127, ks = t >> 7;
    const float* bp = Bl2 + 4*d;
    float ai = 0.f, af = 0.f, ag = 0.f, ao = 0.f;
    #pragma unroll 8
    for (int kk = 0; kk < 96; ++kk){
      int k = ks*96 + kk;
      float a = A_s[k];
      float4 b = *(const float4*)(bp + (size_t)k*512);
      ai += a*b.x; af += a*b.y; ag += a*b.z; ao += a*b.w;
    }
    *(float4*)&part4[ks][d][0] = make_float4(ai, af, ag, ao);
  }
  __syncthreads();
  if (t < D2){
    float4 p0 = *(const float4*)&part4[0][t][0];
    float4 p1 = *(const float4*)&part4[1][t][0];
    float4 p2 = *(const float4*)&part4[2][t][0];
    float4 p3 = *(const float4*)&part4[3][t][0];
    float iv = p0.x+p1.x+p2.x+p3.x + lbih[t]       + lbhh[t];
    float fv = p0.y+p1.y+p2.y+p3.y + lbih[128 + t] + lbhh[128 + t];
    float gv = p0.z+p1.z+p2.z+p3.z + lbih[256 + t] + lbhh[256 + t];
    float ov = p0.w+p1.w+p2.w+p3.w + lbih[384 + t] + lbhh[384 + t];
    float c = sigmoidf_(fv)*cl[(size_t)g*D2 + t] + sigmoidf_(iv)*tanhf(gv);
    float hn = sigmoidf_(ov)*tanhf(c);
    cl[(size_t)g*D2 + t] = c;
    hl[(size_t)g*D2 + t] = hn;
    q_s[t] = hn;
  }
  __syncthreads();
  int n0 = (g*N_NODES + N_GRAPHS - 1)/N_GRAPHS;
  int n1 = ((g+1)*N_NODES + N_GRAPHS - 1)/N_GRAPHS;
  int cnt = n1 - n0;
  float e = -1e30f;
  if (t < cnt){
    int n = n0 + t;
    const float4* xr = (const float4*)(x0 + (size_t)n*H);
    const float4* hr = (const float4*)(h  + (size_t)n*H);
    const float4* q1 = (const float4*)q_s;
    const float4* q2 = (const float4*)(q_s + H);
    float s = 0.0f;
    #pragma unroll
    for (int k4 = 0; k4 < 16; ++k4){
      float4 a = xr[k4], b = q1[k4];
      s += a.x*b.x + a.y*b.y + a.z*b.z + a.w*b.w;
    }
    #pragma unroll
    for (int k4 = 0; k4 < 16; ++k4){
      float4 a = hr[k4], b = q2[k4];
      s += a.x*b.x + a.y*b.y + a.z*b.z + a.w*b.w;
    }
    e = s;
  }
  float mx = e;
  #pragma unroll
  for (int off = 32; off >= 1; off >>= 1) mx = fmaxf(mx, __shfl_xor(mx, off));
  if (lane == 0) wred[w] = mx;
  __syncthreads();
  float gm = wred[0];
  #pragma unroll
  for (int i = 1; i < 8; ++i) gm = fmaxf(gm, wred[i]);
  __syncthreads();
  float ex = (t < cnt) ? expf(e - gm) : 0.0f;
  float sm = ex;
  #pragma unroll
  for (int off = 32; off >= 1; off >>= 1) sm += __shfl_xor(sm, off);
  if (lane == 0) wred[w] = sm;
  __syncthreads();
  float denom = wred[0]+wred[1]+wred[2]+wred[3]+wred[4]+wred[5]+wred[6]+wred[7];
  if (t < cnt) alpha_s[t] = ex / denom;
  __syncthreads();
  float acc0 = 0.f, acc1 = 0.f;
  for (int i = w; i < cnt; i += 8){
    float a = alpha_s[i];
    acc0 += a * x0[(size_t)(n0+i)*H + lane];
    acc1 += a * h [(size_t)(n0+i)*H + lane];
  }
  part[w][lane]      = acc0;
  part[w][64 + lane] = acc1;
  __syncthreads();
  if (t < D2){
    float v = 0.f;
    #pragma unroll
    for (int i = 0; i < 8; ++i) v += part[i][t];
    qstar[(size_t)g*QS + t]      = q_s[t];
    qstar[(size_t)g*QS + D2 + t] = v;
  }
}

// ==================== readout ====================
__global__ __launch_bounds__(256) void out_kernel(
    const float* __restrict__ qstar, const float* __restrict__ Wsp,
    const float* __restrict__ bsp, const float* __restrict__ prelu,
    float* __restrict__ out){
  __shared__ float q_s[QS];
  int g = blockIdx.x & 255;
  int jb = blockIdx.x >> 8;
  int t = threadIdx.x;
  q_s[t] = qstar[(size_t)g*QS + t];
  __syncthreads();
  int j = jb*256 + t;
  const float4* w = (const float4*)(Wsp + (size_t)j*QS);
  const float4* q4 = (const float4*)q_s;
  float acc = bsp[j];
  #pragma unroll
  for (int k4 = 0; k4 < 64; ++k4){
    float4 wv = w[k4]; float4 qv = q4[k4];
    acc += qv.x*wv.x + qv.y*wv.y + qv.z*wv.z + qv.w*wv.w;
  }
  float pw = prelu[0];
  out[(size_t)g*READOUT + j] = (acc >= 0.0f) ? acc : pw*acc;
}

extern "C" void kernel_launch(void* const* d_in, const int* in_sizes, int n_in,
                              void* d_out, int out_size, void* d_ws, size_t ws_size,
                              hipStream_t stream) {
  const float* node_feats = (const float*)d_in[0];
  const float* edge_feats = (const float*)d_in[1];
  const int*   esrc       = (const int*)d_in[2];
  const int*   edst       = (const int*)d_in[3];
  const float* Wproj = (const float*)d_in[5];
  const float* bproj = (const float*)d_in[6];
  const float* Wedge = (const float*)d_in[7];
  const float* bedge = (const float*)d_in[8];
  const float* bconv = (const float*)d_in[9];
  const float* gWih  = (const float*)d_in[10];
  const float* gWhh  = (const float*)d_in[11];
  const float* gbih  = (const float*)d_in[12];
  const float* gbhh  = (const float*)d_in[13];
  const float* lWih  = (const float*)d_in[14];
  const float* lWhh  = (const float*)d_in[15];
  const float* lbih  = (const float*)d_in[16];
  const float* lbhh  = (const float*)d_in[17];
  const float* Wsp   = (const float*)d_in[18];
  const float* bsp   = (const float*)d_in[19];
  const float* prelu = (const float*)d_in[20];

  float* ws    = (float*)d_ws;
  float* x0    = ws;                     // 2,560,000
  float* h     = ws + 2560000;           // 2,560,000
  float* agg   = ws + 5120000;           // 2,560,000
  float* qstar = ws + 7680000;           // 65,536
  float* hl    = qstar + 65536;          // 32,768
  float* cl    = hl + 32768;             // 32,768
  float* Bl2   = agg;                    // s2s phase reuses dead agg (196,608)

  hipMemsetAsync(qstar, 0, (65536 + 32768 + 32768)*sizeof(float), stream);

  pack_we3T<<<272, 256, 0, stream>>>(Wedge, bedge);
  pack_bcT<<<128, 256, 0, stream>>>(gWih, gWhh);

  proj_mm<<<N_NODES/64, 256, 0, stream>>>(node_feats, Wproj, bproj, x0, h);

  for (int s = 0; s < 3; ++s){
    if (s == 0)
      zero_buf<<<2048, 256, 0, stream>>>((float4*)agg, N_NODES*H/4);
    edge_mfma<<<N_EDGES/64, 256, 0, stream>>>(h, edge_feats, esrc, edst, agg);
    gru_mm_mfma<<<N_NODES/64, 256, 0, stream>>>(agg, bconv, h, gbih, gbhh);  // zeroes agg
  }

  build_bl2<<<768, 256, 0, stream>>>(lWih, lWhh, Bl2);

  for (int s = 0; s < 3; ++s){
    s2s_kernel<<<N_GRAPHS, 512, 0, stream>>>(x0, h, Bl2, lbih, lbhh, hl, cl, qstar);
  }

  out_kernel<<<4*N_GRAPHS, 256, 0, stream>>>(qstar, Wsp, bsp, prelu, (float*)d_out);
}

// Round 18
// 312.785 us; speedup vs baseline: 1.3336x; 1.0411x over previous
//
#include <hip/hip_runtime.h>
#include <math.h>

#define H 64
#define NODE_IN 128
#define EDGE_IN 16
#define N_NODES 40000
#define N_EDGES 80000
#define N_GRAPHS 256
#define READOUT 1024
#define D2 128   // 2H
#define QS 256   // 4H

typedef unsigned short u16;
typedef __attribute__((ext_vector_type(8))) short bf16x8;
typedef __attribute__((ext_vector_type(4))) float f32x4;
#define MFMA16(a,b,c) __builtin_amdgcn_mfma_f32_16x16x32_bf16(a,b,c,0,0,0)

// split-bf16 device globals (A/state path keeps hi+lo; weights single bf16-RNE)
__device__ u16 d_xhi[N_NODES*H];
__device__ u16 d_xlo[N_NODES*H];
__device__ u16 d_we3T_hi[64*1088];   // [o][c] bf16-RNE
__device__ u16 d_bcT_hi[256*128];    // bf16-RNE
__device__ float d_wspT[256*1024];   // [k][j] transposed readout weights

__device__ __forceinline__ float sigmoidf_(float x){ return 1.0f/(1.0f + expf(-x)); }

__device__ __forceinline__ u16 bf_hi(float x){
  union { float f; unsigned u; } c; c.f = x;
  unsigned r = (c.u + 0x7FFFu + ((c.u >> 16) & 1u)) >> 16;
  return (u16)r;
}
__device__ __forceinline__ float bf_f(u16 h){
  union { unsigned u; float f; } c; c.u = ((unsigned)h) << 16; return c.f;
}
__device__ __forceinline__ u16 bf_lo(float x, u16 hi){ return bf_hi(x - bf_f(hi)); }

// XOR-swizzled byte offset for [row][64 u16] tiles (128-B rows).
__device__ __forceinline__ int swz(int row, int kq){   // kq = bf16x8 group (0..7)
  return (row*128 + kq*16) ^ ((row & 7) << 4);
}

// RNE-round 8 f32 -> bf16x8 (single stream)
__device__ __forceinline__ bf16x8 rne8(const float* Z){
  union { bf16x8 v; u16 u[8]; } hh;
  #pragma unroll
  for (int k = 0; k < 8; ++k) hh.u[k] = bf_hi(Z[k]);
  return hh.v;
}

// ==================== weight packs (once per launch) ====================
__global__ __launch_bounds__(256) void pack_we3T(
    const float* __restrict__ We, const float* __restrict__ be){
  int i = blockIdx.x*256 + threadIdx.x;     // 69632 = 64*1088
  int o = i / 1088, c = i % 1088;
  float v;
  if (c < 1024){
    int hh = c >> 4, k = c & 15;
    v = We[(size_t)(hh*64 + o)*EDGE_IN + k];
  } else {
    v = be[(size_t)(c - 1024)*64 + o];
  }
  d_we3T_hi[i] = bf_hi(v);
}

__global__ __launch_bounds__(256) void pack_bcT(
    const float* __restrict__ Wih, const float* __restrict__ Whh){
  int i = blockIdx.x*256 + threadIdx.x;     // 32768
  int k = i >> 8, c = i & 255;
  float v;
  if (c < 128){
    v = (k < 64) ? Wih[(size_t)c*H + k] : Whh[(size_t)c*H + (k-64)];
  } else if (c < 192){
    int d = c - 128;
    v = (k < 64) ? Wih[(size_t)(128+d)*H + k] : 0.f;
  } else {
    int d = c - 192;
    v = (k < 64) ? 0.f : Whh[(size_t)(128+d)*H + (k-64)];
  }
  d_bcT_hi[c*128 + k] = bf_hi(v);
}

// readout transpose: read Wsp coalesced, scatter-write d_wspT[k][j]
__global__ __launch_bounds__(256) void pack_wspT(const float* __restrict__ Wsp){
  int i = blockIdx.x*256 + threadIdx.x;     // 262144
  int j = i >> 8, k = i & 255;
  d_wspT[(size_t)k*1024 + j] = Wsp[i];
}

// ==================== zero fill ====================
__global__ __launch_bounds__(256) void zero_buf(float4* __restrict__ p, int n4){
  int i = blockIdx.x*256 + threadIdx.x;
  int stride = gridDim.x*256;
  for (; i < n4; i += stride) p[i] = make_float4(0.f,0.f,0.f,0.f);
}

// ==================== proj GEMM ====================
__global__ __launch_bounds__(256) void proj_mm(
    const float* __restrict__ nf, const float* __restrict__ Wp,
    const float* __restrict__ bp, float* __restrict__ x0, float* __restrict__ h){
  __shared__ float A_s[NODE_IN][64];
  __shared__ float B_s[NODE_IN][64];
  int t = threadIdx.x;
  int nb = blockIdx.x * 64;
  #pragma unroll
  for (int p = 0; p < 8; ++p){
    int idx = p*256 + t;
    int n = idx >> 5, k4 = idx & 31;
    float4 v = ((const float4*)(nf + (size_t)(nb+n)*NODE_IN))[k4];
    int base = (((n>>2) ^ (k4 & 15)) << 2) + (n & 3);
    A_s[k4*4+0][base]=v.x; A_s[k4*4+1][base]=v.y;
    A_s[k4*4+2][base]=v.z; A_s[k4*4+3][base]=v.w;
  }
  #pragma unroll
  for (int p = 0; p < 8; ++p){
    int idx = p*256 + t;
    int c = idx & 63, k4 = idx >> 6;
    float4 v = ((const float4*)(Wp + (size_t)c*NODE_IN))[k4];
    B_s[k4*4+0][c]=v.x; B_s[k4*4+1][c]=v.y; B_s[k4*4+2][c]=v.z; B_s[k4*4+3][c]=v.w;
  }
  __syncthreads();
  int eg = t & 15, cg = t >> 4;
  float acc[4][4] = {};
  #pragma unroll 4
  for (int k = 0; k < NODE_IN; ++k){
    int s = (k >> 2) & 15;
    float4 a = *(const float4*)&A_s[k][(eg ^ s) << 2];
    float4 b = *(const float4*)&B_s[k][cg*4];
    float av[4] = {a.x,a.y,a.z,a.w};
    float bv[4] = {b.x,b.y,b.z,b.w};
    #pragma unroll
    for (int j = 0; j < 4; ++j)
      #pragma unroll
      for (int c = 0; c < 4; ++c) acc[j][c] += av[j]*bv[c];
  }
  float4 bb = ((const float4*)bp)[cg];
  float bv[4] = {bb.x,bb.y,bb.z,bb.w};
  #pragma unroll
  for (int j = 0; j < 4; ++j){
    int n = nb + eg*4 + j;
    float o[4];
    #pragma unroll
    for (int c = 0; c < 4; ++c) o[c] = fmaxf(acc[j][c]+bv[c], 0.f);
    *(float4*)(x0 + (size_t)n*H + cg*4) = make_float4(o[0],o[1],o[2],o[3]);
    *(float4*)(h  + (size_t)n*H + cg*4) = make_float4(o[0],o[1],o[2],o[3]);
    u16 hs[4], ls[4];
    #pragma unroll
    for (int c = 0; c < 4; ++c){ hs[c] = bf_hi(o[c]); ls[c] = bf_lo(o[c], hs[c]); }
    *(ushort4*)&d_xhi[(size_t)n*H + cg*4] = make_ushort4(hs[0],hs[1],hs[2],hs[3]);
    *(ushort4*)&d_xlo[(size_t)n*H + cg*4] = make_ushort4(ls[0],ls[1],ls[2],ls[3]);
  }
}

// ==================== fused edge message (A and B single-stream bf16) ====
__global__ __launch_bounds__(256) void edge_mfma(
    const float* __restrict__ xf, const float* __restrict__ ef,
    const int* __restrict__ src, const int* __restrict__ dst,
    float* __restrict__ agg){
  __shared__ __align__(16) char smem[16384];   // B dbuf: 2 x 8K
  __shared__ __align__(16) float x_s[64][68];  // 17.4 KB; msg overlay at flush
  __shared__ int src_s[64], dst_s[64];
  float* msg_s = (float*)x_s;

  int t = threadIdx.x;
  int w = t >> 6, lane = t & 63;
  int m = lane & 15, kq = lane >> 4;
  int ebase = blockIdx.x * 64;
  int e0 = t >> 2, j4 = t & 3;
  if (t < 64){ src_s[t] = src[ebase + t]; dst_s[t] = dst[ebase + t]; }
  { // stage B chunk 0 -> buf0
    const u16* gh = d_we3T_hi + (size_t)e0*1088 + j4*16;
    int b0 = swz(e0, 2*j4), b1 = swz(e0, 2*j4+1);
    *(bf16x8*)(smem + b0) = *(const bf16x8*)gh;
    *(bf16x8*)(smem + b1) = *(const bf16x8*)(gh+8);
  }
  __syncthreads();
  { // stage x rows
    const float4* px = (const float4*)(xf + (size_t)src_s[e0]*H + j4*16);
    float4 v0=px[0], v1=px[1], v2=px[2], v3=px[3];
    float* xr = &x_s[e0][j4*16];
    *(float4*)xr      = v0;
    *(float4*)(xr+4)  = v1;
    *(float4*)(xr+8)  = v2;
    *(float4*)(xr+12) = v3;
  }
  int e = w*16 + m;
  float ef8[8];
  {
    const float4* p = (const float4*)(ef + (size_t)(ebase+e)*EDGE_IN + (kq&1)*8);
    float4 a = p[0], b = p[1];
    ef8[0]=a.x; ef8[1]=a.y; ef8[2]=a.z; ef8[3]=a.w;
    ef8[4]=b.x; ef8[5]=b.y; ef8[6]=b.z; ef8[7]=b.w;
  }
  __syncthreads();

  int hsel = kq >> 1;
  f32x4 acc[4];
  #pragma unroll
  for (int i = 0; i < 4; ++i) acc[i] = (f32x4){0.f,0.f,0.f,0.f};

  #pragma unroll 2
  for (int ci = 0; ci < 16; ++ci){
    bf16x8 pbh0, pbh1;
    {
      const u16* gh = d_we3T_hi + (size_t)e0*1088 + (ci+1)*64 + j4*16;
      pbh0 = *(const bf16x8*)gh; pbh1 = *(const bf16x8*)(gh+8);
    }
    float x0v = x_s[e][ci*4 + hsel];
    float x1v = x_s[e][ci*4 + 2 + hsel];
    float Z0[8], Z1[8];
    #pragma unroll
    for (int j = 0; j < 8; ++j){ Z0[j] = x0v*ef8[j]; Z1[j] = x1v*ef8[j]; }
    bf16x8 a0 = rne8(Z0), a1 = rne8(Z1);
    {
      char* BhC = smem + (ci & 1)*8192;
      #pragma unroll
      for (int nt = 0; nt < 4; ++nt){
        int rb = nt*16 + m;
        int c0 = swz(rb, kq), c1 = c0 ^ 64;
        bf16x8 bh0 = *(const bf16x8*)(BhC + c0);
        bf16x8 bh1 = *(const bf16x8*)(BhC + c1);
        acc[nt] = MFMA16(a0, bh0, acc[nt]);
        acc[nt] = MFMA16(a1, bh1, acc[nt]);
      }
    }
    {
      char* BhN = smem + ((ci+1) & 1)*8192;
      int b0 = swz(e0, 2*j4), b1 = swz(e0, 2*j4+1);
      *(bf16x8*)(BhN + b0) = pbh0;
      *(bf16x8*)(BhN + b1) = pbh1;
    }
    __syncthreads();
  }
  { // bias chunk (ci=16) lands in buf0
    float xb[16];
    {
      const float4* q0 = (const float4*)&x_s[e][kq*8];
      const float4* q1 = (const float4*)&x_s[e][32 + kq*8];
      float4 a=q0[0], b=q0[1], c=q1[0], d=q1[1];
      xb[0]=a.x; xb[1]=a.y; xb[2]=a.z; xb[3]=a.w;
      xb[4]=b.x; xb[5]=b.y; xb[6]=b.z; xb[7]=b.w;
      xb[8]=c.x; xb[9]=c.y; xb[10]=c.z; xb[11]=c.w;
      xb[12]=d.x; xb[13]=d.y; xb[14]=d.z; xb[15]=d.w;
    }
    bf16x8 a0 = rne8(xb), a1 = rne8(xb + 8);
    char* BhC = smem;
    #pragma unroll
    for (int nt = 0; nt < 4; ++nt){
      int rb = nt*16 + m;
      int c0 = swz(rb, kq), c1 = c0 ^ 64;
      bf16x8 bh0 = *(const bf16x8*)(BhC + c0);
      bf16x8 bh1 = *(const bf16x8*)(BhC + c1);
      acc[nt] = MFMA16(a0, bh0, acc[nt]);
      acc[nt] = MFMA16(a1, bh1, acc[nt]);
    }
  }
  __syncthreads();
  #pragma unroll
  for (int nt = 0; nt < 4; ++nt){
    int o = nt*16 + m;
    #pragma unroll
    for (int r = 0; r < 4; ++r){
      int ee = w*16 + kq*4 + r;
      msg_s[ee*64 + (o ^ ((ee & 7) << 2))] = acc[nt][r];
    }
  }
  __syncthreads();
  #pragma unroll
  for (int r = 0; r < 16; ++r){
    int ee = w*16 + r;
    atomicAdd(&agg[(size_t)dst_s[ee]*H + lane],
              msg_s[ee*64 + (lane ^ ((ee & 7) << 2))]);
  }
}

// ==================== GRU GEMM + fused epilogue (B single-stream bf16) ====
__global__ __launch_bounds__(256) void gru_mm_mfma(
    float* __restrict__ agg, const float* __restrict__ bconv,
    float* __restrict__ h, const float* __restrict__ gbih,
    const float* __restrict__ gbhh){
  __shared__ u16 Ah[64][40], Al[64][40];
  __shared__ u16 Bh[256][40];
  __shared__ float bih_s[192], bhh_s[192];
  int t = threadIdx.x;
  int w = t >> 6, lane = t & 63;
  int nb = blockIdx.x * 64;
  if (t < 192){ bih_s[t] = gbih[t]; bhh_s[t] = gbhh[t]; }
  int m = lane & 15, kj = (lane >> 4) * 8;
  f32x4 acc[16];
  #pragma unroll
  for (int i = 0; i < 16; ++i) acc[i] = (f32x4){0.f,0.f,0.f,0.f};
  bf16x8 pbh[4];
  #pragma unroll
  for (int qq = 0; qq < 4; ++qq)
    pbh[qq] = *(const bf16x8*)&d_bcT_hi[t*128 + qq*8];
  for (int kc = 0; kc < 4; ++kc){
    __syncthreads();
    {
      int n = t >> 2, q = t & 3;
      if (kc < 2){
        float* sp = agg + (size_t)(nb+n)*H + kc*32 + q*8;
        float4 v0 = *(const float4*)sp;
        float4 v1 = *(const float4*)(sp + 4);
        float4 b0 = *(const float4*)&bconv[kc*32 + q*8];
        float4 b1 = *(const float4*)&bconv[kc*32 + q*8 + 4];
        *(float4*)sp       = make_float4(0.f,0.f,0.f,0.f);
        *(float4*)(sp + 4) = make_float4(0.f,0.f,0.f,0.f);
        float vals[8] = { fmaxf(v0.x+b0.x,0.f), fmaxf(v0.y+b0.y,0.f),
                          fmaxf(v0.z+b0.z,0.f), fmaxf(v0.w+b0.w,0.f),
                          fmaxf(v1.x+b1.x,0.f), fmaxf(v1.y+b1.y,0.f),
                          fmaxf(v1.z+b1.z,0.f), fmaxf(v1.w+b1.w,0.f) };
        union { bf16x8 v; u16 u[8]; } ph, pl;
        #pragma unroll
        for (int j = 0; j < 8; ++j){
          u16 hi = bf_hi(vals[j]);
          ph.u[j] = hi; pl.u[j] = bf_lo(vals[j], hi);
        }
        *(bf16x8*)&Ah[n][q*8] = ph.v;
        *(bf16x8*)&Al[n][q*8] = pl.v;
      } else {
        int gofs = (nb+n)*H + (kc-2)*32 + q*8;
        *(bf16x8*)&Ah[n][q*8] = *(const bf16x8*)&d_xhi[gofs];
        *(bf16x8*)&Al[n][q*8] = *(const bf16x8*)&d_xlo[gofs];
      }
    }
    #pragma unroll
    for (int qq = 0; qq < 4; ++qq)
      *(bf16x8*)&Bh[t][qq*8] = pbh[qq];
    if (kc < 3){
      #pragma unroll
      for (int qq = 0; qq < 4; ++qq)
        pbh[qq] = *(const bf16x8*)&d_bcT_hi[t*128 + (kc+1)*32 + qq*8];
    }
    __syncthreads();
    bf16x8 ah = *(const bf16x8*)&Ah[w*16 + m][kj];
    bf16x8 al = *(const bf16x8*)&Al[w*16 + m][kj];
    #pragma unroll
    for (int nt = 0; nt < 16; ++nt){
      bf16x8 bh = *(const bf16x8*)&Bh[nt*16 + m][kj];
      acc[nt] = MFMA16(ah, bh, acc[nt]);
      acc[nt] = MFMA16(al, bh, acc[nt]);
    }
  }
  int q4 = lane >> 4, col0 = lane & 15;
  #pragma unroll
  for (int r = 0; r < 4; ++r){
    int node = nb + w*16 + q4*4 + r;
    #pragma unroll
    for (int j = 0; j < 4; ++j){
      int d = col0 + 16*j;
      float rg = sigmoidf_(acc[j][r]   + bih_s[d]      + bhh_s[d]);
      float z  = sigmoidf_(acc[4+j][r] + bih_s[64+d]   + bhh_s[64+d]);
      float nn = tanhf(acc[8+j][r] + bih_s[128+d] + rg*(acc[12+j][r] + bhh_s[128+d]));
      size_t off = (size_t)node*H + d;
      float hv = h[off];
      float hn = (1.f - z)*nn + z*hv;
      h[off] = hn;
      u16 hb = bf_hi(hn);
      d_xhi[off] = hb;
      d_xlo[off] = bf_lo(hn, hb);
    }
  }
}

// ==================== Bl2 pack ====================
__global__ __launch_bounds__(256) void build_bl2(
    const float* __restrict__ Wih, const float* __restrict__ Whh,
    float* __restrict__ Bl2){
  int i = blockIdx.x*256 + threadIdx.x;   // 196608
  int k = i >> 9, c = i & 511;
  int d = c >> 2, gate = c & 3;
  int row = gate*128 + d;
  float v = (k < 256) ? Wih[(size_t)row*QS + k] : Whh[(size_t)row*D2 + (k-256)];
  Bl2[i] = v;
}

// ==================== fused Set2Set step: LSTM cell + attention (512 thr) ====
__global__ __launch_bounds__(512) void s2s_kernel(
    const float* __restrict__ x0, const float* __restrict__ h,
    const float* __restrict__ Bl2, const float* __restrict__ lbih,
    const float* __restrict__ lbhh, float* __restrict__ hl,
    float* __restrict__ cl, float* __restrict__ qstar){
  __shared__ float A_s[384];
  __shared__ float part4[4][128][4];
  __shared__ float q_s[D2];
  __shared__ float alpha_s[160];
  __shared__ float wred[8];
  __shared__ float part[8][D2];
  int g = blockIdx.x, t = threadIdx.x;
  int lane = t & 63, w = t >> 6;
  if (t < 384){
    A_s[t] = (t < 256) ? qstar[(size_t)g*QS + t] : hl[(size_t)g*D2 + (t - 256)];
  }
  __syncthreads();
  {
    int d = t & 127, ks = t >> 7;
    const float* bp = Bl2 + 4*d;
    float ai = 0.f, af = 0.f, ag = 0.f, ao = 0.f;
    #pragma unroll 8
    for (int kk = 0; kk < 96; ++kk){
      int k = ks*96 + kk;
      float a = A_s[k];
      float4 b = *(const float4*)(bp + (size_t)k*512);
      ai += a*b.x; af += a*b.y; ag += a*b.z; ao += a*b.w;
    }
    *(float4*)&part4[ks][d][0] = make_float4(ai, af, ag, ao);
  }
  __syncthreads();
  if (t < D2){
    float4 p0 = *(const float4*)&part4[0][t][0];
    float4 p1 = *(const float4*)&part4[1][t][0];
    float4 p2 = *(const float4*)&part4[2][t][0];
    float4 p3 = *(const float4*)&part4[3][t][0];
    float iv = p0.x+p1.x+p2.x+p3.x + lbih[t]       + lbhh[t];
    float fv = p0.y+p1.y+p2.y+p3.y + lbih[128 + t] + lbhh[128 + t];
    float gv = p0.z+p1.z+p2.z+p3.z + lbih[256 + t] + lbhh[256 + t];
    float ov = p0.w+p1.w+p2.w+p3.w + lbih[384 + t] + lbhh[384 + t];
    float c = sigmoidf_(fv)*cl[(size_t)g*D2 + t] + sigmoidf_(iv)*tanhf(gv);
    float hn = sigmoidf_(ov)*tanhf(c);
    cl[(size_t)g*D2 + t] = c;
    hl[(size_t)g*D2 + t] = hn;
    q_s[t] = hn;
  }
  __syncthreads();
  int n0 = (g*N_NODES + N_GRAPHS - 1)/N_GRAPHS;
  int n1 = ((g+1)*N_NODES + N_GRAPHS - 1)/N_GRAPHS;
  int cnt = n1 - n0;
  float e = -1e30f;
  if (t < cnt){
    int n = n0 + t;
    const float4* xr = (const float4*)(x0 + (size_t)n*H);
    const float4* hr = (const float4*)(h  + (size_t)n*H);
    const float4* q1 = (const float4*)q_s;
    const float4* q2 = (const float4*)(q_s + H);
    float s = 0.0f;
    #pragma unroll
    for (int k4 = 0; k4 < 16; ++k4){
      float4 a = xr[k4], b = q1[k4];
      s += a.x*b.x + a.y*b.y + a.z*b.z + a.w*b.w;
    }
    #pragma unroll
    for (int k4 = 0; k4 < 16; ++k4){
      float4 a = hr[k4], b = q2[k4];
      s += a.x*b.x + a.y*b.y + a.z*b.z + a.w*b.w;
    }
    e = s;
  }
  float mx = e;
  #pragma unroll
  for (int off = 32; off >= 1; off >>= 1) mx = fmaxf(mx, __shfl_xor(mx, off));
  if (lane == 0) wred[w] = mx;
  __syncthreads();
  float gm = wred[0];
  #pragma unroll
  for (int i = 1; i < 8; ++i) gm = fmaxf(gm, wred[i]);
  __syncthreads();
  float ex = (t < cnt) ? expf(e - gm) : 0.0f;
  float sm = ex;
  #pragma unroll
  for (int off = 32; off >= 1; off >>= 1) sm += __shfl_xor(sm, off);
  if (lane == 0) wred[w] = sm;
  __syncthreads();
  float denom = wred[0]+wred[1]+wred[2]+wred[3]+wred[4]+wred[5]+wred[6]+wred[7];
  if (t < cnt) alpha_s[t] = ex / denom;
  __syncthreads();
  float acc0 = 0.f, acc1 = 0.f;
  for (int i = w; i < cnt; i += 8){
    float a = alpha_s[i];
    acc0 += a * x0[(size_t)(n0+i)*H + lane];
    acc1 += a * h [(size_t)(n0+i)*H + lane];
  }
  part[w][lane]      = acc0;
  part[w][64 + lane] = acc1;
  __syncthreads();
  if (t < D2){
    float v = 0.f;
    #pragma unroll
    for (int i = 0; i < 8; ++i) v += part[i][t];
    qstar[(size_t)g*QS + t]      = q_s[t];
    qstar[(size_t)g*QS + D2 + t] = v;
  }
}

// ==================== readout (coalesced, transposed weights) ====================
// out[g][j] = PReLU(sum_k qstar[g][k] * wspT[k][j] + bsp[j])
// grid 512: (g, half); thread t covers j = half*512 + t and +256.
__global__ __launch_bounds__(256) void out_kernel(
    const float* __restrict__ qstar, const float* __restrict__ bsp,
    const float* __restrict__ prelu, float* __restrict__ out){
  __shared__ float q_s[QS];
  int g = blockIdx.x >> 1, half = blockIdx.x & 1;
  int t = threadIdx.x;
  q_s[t] = qstar[(size_t)g*QS + t];
  __syncthreads();
  int j0 = half*512 + t;
  float acc0 = bsp[j0], acc1 = bsp[j0 + 256];
  const float* wp = d_wspT + j0;
  #pragma unroll 4
  for (int k = 0; k < QS; ++k){
    float q = q_s[k];
    acc0 += q * wp[(size_t)k*1024];
    acc1 += q * wp[(size_t)k*1024 + 256];
  }
  float pw = prelu[0];
  out[(size_t)g*READOUT + j0]       = (acc0 >= 0.0f) ? acc0 : pw*acc0;
  out[(size_t)g*READOUT + j0 + 256] = (acc1 >= 0.0f) ? acc1 : pw*acc1;
}

extern "C" void kernel_launch(void* const* d_in, const int* in_sizes, int n_in,
                              void* d_out, int out_size, void* d_ws, size_t ws_size,
                              hipStream_t stream) {
  const float* node_feats = (const float*)d_in[0];
  const float* edge_feats = (const float*)d_in[1];
  const int*   esrc       = (const int*)d_in[2];
  const int*   edst       = (const int*)d_in[3];
  const float* Wproj = (const float*)d_in[5];
  const float* bproj = (const float*)d_in[6];
  const float* Wedge = (const float*)d_in[7];
  const float* bedge = (const float*)d_in[8];
  const float* bconv = (const float*)d_in[9];
  const float* gWih  = (const float*)d_in[10];
  const float* gWhh  = (const float*)d_in[11];
  const float* gbih  = (const float*)d_in[12];
  const float* gbhh  = (const float*)d_in[13];
  const float* lWih  = (const float*)d_in[14];
  const float* lWhh  = (const float*)d_in[15];
  const float* lbih  = (const float*)d_in[16];
  const float* lbhh  = (const float*)d_in[17];
  const float* Wsp   = (const float*)d_in[18];
  const float* bsp   = (const float*)d_in[19];
  const float* prelu = (const float*)d_in[20];

  float* ws    = (float*)d_ws;
  float* x0    = ws;                     // 2,560,000
  float* h     = ws + 2560000;           // 2,560,000
  float* agg   = ws + 5120000;           // 2,560,000
  float* qstar = ws + 7680000;           // 65,536
  float* hl    = qstar + 65536;          // 32,768
  float* cl    = hl + 32768;             // 32,768
  float* Bl2   = agg;                    // s2s phase reuses dead agg (196,608)

  hipMemsetAsync(qstar, 0, (65536 + 32768 + 32768)*sizeof(float), stream);

  pack_we3T<<<272, 256, 0, stream>>>(Wedge, bedge);
  pack_bcT<<<128, 256, 0, stream>>>(gWih, gWhh);
  pack_wspT<<<1024, 256, 0, stream>>>(Wsp);

  proj_mm<<<N_NODES/64, 256, 0, stream>>>(node_feats, Wproj, bproj, x0, h);

  for (int s = 0; s < 3; ++s){
    if (s == 0)
      zero_buf<<<2048, 256, 0, stream>>>((float4*)agg, N_NODES*H/4);
    edge_mfma<<<N_EDGES/64, 256, 0, stream>>>(h, edge_feats, esrc, edst, agg);
    gru_mm_mfma<<<N_NODES/64, 256, 0, stream>>>(agg, bconv, h, gbih, gbhh);  // zeroes agg
  }

  build_bl2<<<768, 256, 0, stream>>>(lWih, lWhh, Bl2);

  for (int s = 0; s < 3; ++s){
    s2s_kernel<<<N_GRAPHS, 512, 0, stream>>>(x0, h, Bl2, lbih, lbhh, hl, cl, qstar);
  }

  out_kernel<<<2*N_GRAPHS, 256, 0, stream>>>(qstar, bsp, prelu, (float*)d_out);
}

// Round 19
// 312.747 us; speedup vs baseline: 1.3338x; 1.0001x over previous
//
#include <hip/hip_runtime.h>
#include <math.h>

#define H 64
#define NODE_IN 128
#define EDGE_IN 16
#define N_NODES 40000
#define N_EDGES 80000
#define N_GRAPHS 256
#define READOUT 1024
#define D2 128   // 2H
#define QS 256   // 4H

typedef unsigned short u16;
typedef __attribute__((ext_vector_type(8))) short bf16x8;
typedef __attribute__((ext_vector_type(4))) float f32x4;
#define MFMA16(a,b,c) __builtin_amdgcn_mfma_f32_16x16x32_bf16(a,b,c,0,0,0)

// device globals
__device__ u16 d_xhi[N_NODES*H];
__device__ u16 d_xlo[N_NODES*H];
// edge weights in MFMA FRAGMENT order: [((ci*4+nt)*2+half)*64+lane] x bf16x8
__device__ u16 d_weF[17*4*2*64*8];
// gru weights in fragment order: [(kc*16+nt)*64+lane] x bf16x8
__device__ u16 d_bcF[4*16*64*8];
__device__ float d_wspT[256*1024];

__device__ __forceinline__ float sigmoidf_(float x){ return 1.0f/(1.0f + expf(-x)); }

__device__ __forceinline__ u16 bf_hi(float x){
  union { float f; unsigned u; } c; c.f = x;
  unsigned r = (c.u + 0x7FFFu + ((c.u >> 16) & 1u)) >> 16;
  return (u16)r;
}
__device__ __forceinline__ float bf_f(u16 h){
  union { unsigned u; float f; } c; c.u = ((unsigned)h) << 16; return c.f;
}
__device__ __forceinline__ u16 bf_lo(float x, u16 hi){ return bf_hi(x - bf_f(hi)); }

// RNE-round 8 f32 -> bf16x8
__device__ __forceinline__ bf16x8 rne8(const float* Z){
  union { bf16x8 v; u16 u[8]; } hh;
  #pragma unroll
  for (int k = 0; k < 8; ++k) hh.u[k] = bf_hi(Z[k]);
  return hh.v;
}

// ==================== weight packs (once per launch) ====================
// edge weights -> fragment order. c = ci*64 + half*32 + kq*8 + j
__global__ __launch_bounds__(256) void pack_weF(
    const float* __restrict__ We, const float* __restrict__ be){
  int i = blockIdx.x*256 + threadIdx.x;     // 69632
  int j = i & 7, lane = (i >> 3) & 63, half = (i >> 9) & 1;
  int nt = (i >> 10) & 3, ci = i >> 12;
  int o = nt*16 + (lane & 15);
  int c = ci*64 + half*32 + (lane >> 4)*8 + j;
  float v = (c < 1024) ? We[(size_t)((c >> 4)*64 + o)*EDGE_IN + (c & 15)]
                       : be[(size_t)(c - 1024)*64 + o];
  d_weF[i] = bf_hi(v);
}

// gru weights -> fragment order. row c_row = nt*16+(lane&15), k = kc*32+(lane>>4)*8+j
__global__ __launch_bounds__(256) void pack_bcF(
    const float* __restrict__ Wih, const float* __restrict__ Whh){
  int i = blockIdx.x*256 + threadIdx.x;     // 32768
  int j = i & 7, lane = (i >> 3) & 63, nt = (i >> 9) & 15, kc = i >> 13;
  int cr = nt*16 + (lane & 15);
  int k  = kc*32 + (lane >> 4)*8 + j;
  float v;
  if (cr < 128){
    v = (k < 64) ? Wih[(size_t)cr*H + k] : Whh[(size_t)cr*H + (k-64)];
  } else if (cr < 192){
    int d = cr - 128;
    v = (k < 64) ? Wih[(size_t)(128+d)*H + k] : 0.f;
  } else {
    int d = cr - 192;
    v = (k < 64) ? 0.f : Whh[(size_t)(128+d)*H + (k-64)];
  }
  d_bcF[i] = bf_hi(v);
}

__global__ __launch_bounds__(256) void pack_wspT(const float* __restrict__ Wsp){
  int i = blockIdx.x*256 + threadIdx.x;     // 262144
  int j = i >> 8, k = i & 255;
  d_wspT[(size_t)k*1024 + j] = Wsp[i];
}

// ==================== zero fill ====================
__global__ __launch_bounds__(256) void zero_buf(float4* __restrict__ p, int n4){
  int i = blockIdx.x*256 + threadIdx.x;
  int stride = gridDim.x*256;
  for (; i < n4; i += stride) p[i] = make_float4(0.f,0.f,0.f,0.f);
}

// ==================== proj GEMM ====================
__global__ __launch_bounds__(256) void proj_mm(
    const float* __restrict__ nf, const float* __restrict__ Wp,
    const float* __restrict__ bp, float* __restrict__ x0, float* __restrict__ h){
  __shared__ float A_s[NODE_IN][64];
  __shared__ float B_s[NODE_IN][64];
  int t = threadIdx.x;
  int nb = blockIdx.x * 64;
  #pragma unroll
  for (int p = 0; p < 8; ++p){
    int idx = p*256 + t;
    int n = idx >> 5, k4 = idx & 31;
    float4 v = ((const float4*)(nf + (size_t)(nb+n)*NODE_IN))[k4];
    int base = (((n>>2) ^ (k4 & 15)) << 2) + (n & 3);
    A_s[k4*4+0][base]=v.x; A_s[k4*4+1][base]=v.y;
    A_s[k4*4+2][base]=v.z; A_s[k4*4+3][base]=v.w;
  }
  #pragma unroll
  for (int p = 0; p < 8; ++p){
    int idx = p*256 + t;
    int c = idx & 63, k4 = idx >> 6;
    float4 v = ((const float4*)(Wp + (size_t)c*NODE_IN))[k4];
    B_s[k4*4+0][c]=v.x; B_s[k4*4+1][c]=v.y; B_s[k4*4+2][c]=v.z; B_s[k4*4+3][c]=v.w;
  }
  __syncthreads();
  int eg = t & 15, cg = t >> 4;
  float acc[4][4] = {};
  #pragma unroll 4
  for (int k = 0; k < NODE_IN; ++k){
    int s = (k >> 2) & 15;
    float4 a = *(const float4*)&A_s[k][(eg ^ s) << 2];
    float4 b = *(const float4*)&B_s[k][cg*4];
    float av[4] = {a.x,a.y,a.z,a.w};
    float bv[4] = {b.x,b.y,b.z,b.w};
    #pragma unroll
    for (int j = 0; j < 4; ++j)
      #pragma unroll
      for (int c = 0; c < 4; ++c) acc[j][c] += av[j]*bv[c];
  }
  float4 bb = ((const float4*)bp)[cg];
  float bv[4] = {bb.x,bb.y,bb.z,bb.w};
  #pragma unroll
  for (int j = 0; j < 4; ++j){
    int n = nb + eg*4 + j;
    float o[4];
    #pragma unroll
    for (int c = 0; c < 4; ++c) o[c] = fmaxf(acc[j][c]+bv[c], 0.f);
    *(float4*)(x0 + (size_t)n*H + cg*4) = make_float4(o[0],o[1],o[2],o[3]);
    *(float4*)(h  + (size_t)n*H + cg*4) = make_float4(o[0],o[1],o[2],o[3]);
    u16 hs[4], ls[4];
    #pragma unroll
    for (int c = 0; c < 4; ++c){ hs[c] = bf_hi(o[c]); ls[c] = bf_lo(o[c], hs[c]); }
    *(ushort4*)&d_xhi[(size_t)n*H + cg*4] = make_ushort4(hs[0],hs[1],hs[2],hs[3]);
    *(ushort4*)&d_xlo[(size_t)n*H + cg*4] = make_ushort4(ls[0],ls[1],ls[2],ls[3]);
  }
}

// ==================== fused edge message: BARRIER-FREE ====
// B fragments loaded coalesced from L2 (fragment-packed d_weF); x_s rows,
// ef, msg rows, flush all wave-private (wave w owns edges w*16..w*16+15)
// -> zero __syncthreads; waves fully independent. LDS 17.4 KB -> 8 blocks/CU.
__global__ __launch_bounds__(256) void edge_mfma(
    const float* __restrict__ xf, const float* __restrict__ ef,
    const int* __restrict__ src, const int* __restrict__ dst,
    float* __restrict__ agg){
  __shared__ __align__(16) float x_s[64][68];   // msg overlay (stride 68, wave-private)
  int t = threadIdx.x;
  int w = t >> 6, lane = t & 63;
  int m = lane & 15, kq = lane >> 4;
  int ebase = blockIdx.x * 64;
  int e0 = t >> 2, j4 = t & 3;     // e0 in [w*16, w*16+16): own-wave rows
  { // stage own x row quarter
    int s0 = src[ebase + e0];
    const float4* px = (const float4*)(xf + (size_t)s0*H + j4*16);
    float4 v0=px[0], v1=px[1], v2=px[2], v3=px[3];
    float* xr = &x_s[e0][j4*16];
    *(float4*)xr      = v0;
    *(float4*)(xr+4)  = v1;
    *(float4*)(xr+8)  = v2;
    *(float4*)(xr+12) = v3;
  }
  int e = w*16 + m;
  float ef8[8];
  {
    const float4* p = (const float4*)(ef + (size_t)(ebase+e)*EDGE_IN + (kq&1)*8);
    float4 a = p[0], b = p[1];
    ef8[0]=a.x; ef8[1]=a.y; ef8[2]=a.z; ef8[3]=a.w;
    ef8[4]=b.x; ef8[5]=b.y; ef8[6]=b.z; ef8[7]=b.w;
  }
  int hsel = kq >> 1;
  const bf16x8* wF = (const bf16x8*)d_weF + lane;   // fragment stride 64
  f32x4 acc[4];
  #pragma unroll
  for (int i = 0; i < 4; ++i) acc[i] = (f32x4){0.f,0.f,0.f,0.f};

  #pragma unroll 2
  for (int ci = 0; ci < 16; ++ci){
    float x0v = x_s[e][ci*4 + hsel];
    float x1v = x_s[e][ci*4 + 2 + hsel];
    float Z0[8], Z1[8];
    #pragma unroll
    for (int j = 0; j < 8; ++j){ Z0[j] = x0v*ef8[j]; Z1[j] = x1v*ef8[j]; }
    bf16x8 a0 = rne8(Z0), a1 = rne8(Z1);
    #pragma unroll
    for (int nt = 0; nt < 4; ++nt){
      bf16x8 b0 = wF[(size_t)((ci*4+nt)*2 + 0)*64];
      bf16x8 b1 = wF[(size_t)((ci*4+nt)*2 + 1)*64];
      acc[nt] = MFMA16(a0, b0, acc[nt]);
      acc[nt] = MFMA16(a1, b1, acc[nt]);
    }
  }
  { // bias chunk (ci = 16)
    float xb[16];
    {
      const float4* q0 = (const float4*)&x_s[e][kq*8];
      const float4* q1 = (const float4*)&x_s[e][32 + kq*8];
      float4 a=q0[0], b=q0[1], c=q1[0], d=q1[1];
      xb[0]=a.x; xb[1]=a.y; xb[2]=a.z; xb[3]=a.w;
      xb[4]=b.x; xb[5]=b.y; xb[6]=b.z; xb[7]=b.w;
      xb[8]=c.x; xb[9]=c.y; xb[10]=c.z; xb[11]=c.w;
      xb[12]=d.x; xb[13]=d.y; xb[14]=d.z; xb[15]=d.w;
    }
    bf16x8 a0 = rne8(xb), a1 = rne8(xb + 8);
    #pragma unroll
    for (int nt = 0; nt < 4; ++nt){
      bf16x8 b0 = wF[(size_t)((64+nt)*2 + 0)*64];
      bf16x8 b1 = wF[(size_t)((64+nt)*2 + 1)*64];
      acc[nt] = MFMA16(a0, b0, acc[nt]);
      acc[nt] = MFMA16(a1, b1, acc[nt]);
    }
  }
  // msg overlay (stride 68 keeps rows wave-private; own-wave LDS is in-order)
  float* msg_s = (float*)x_s;
  #pragma unroll
  for (int nt = 0; nt < 4; ++nt){
    int o = nt*16 + m;
    #pragma unroll
    for (int r = 0; r < 4; ++r){
      int ee = w*16 + kq*4 + r;
      msg_s[ee*68 + (o ^ ((ee & 7) << 2))] = acc[nt][r];
    }
  }
  // coalesced atomic flush (own edges)
  #pragma unroll
  for (int r = 0; r < 16; ++r){
    int ee = w*16 + r;
    int dn = dst[ebase + ee];
    atomicAdd(&agg[(size_t)dn*H + lane],
              msg_s[ee*68 + (lane ^ ((ee & 7) << 2))]);
  }
}

// ==================== GRU GEMM + fused epilogue; B from L2 fragments ====
// A staging wave-private (rows w*16..+15) -> no K-loop barriers; one barrier
// before epilogue for bias LDS. Zeroes agg rows after reading.
__global__ __launch_bounds__(256) void gru_mm_mfma(
    float* __restrict__ agg, const float* __restrict__ bconv,
    float* __restrict__ h, const float* __restrict__ gbih,
    const float* __restrict__ gbhh){
  __shared__ u16 Ah[64][40], Al[64][40];
  __shared__ float bih_s[192], bhh_s[192];
  int t = threadIdx.x;
  int w = t >> 6, lane = t & 63;
  int nb = blockIdx.x * 64;
  if (t < 192){ bih_s[t] = gbih[t]; bhh_s[t] = gbhh[t]; }
  int m = lane & 15, kj = (lane >> 4) * 8;
  const bf16x8* bF = (const bf16x8*)d_bcF + lane;
  f32x4 acc[16];
  #pragma unroll
  for (int i = 0; i < 16; ++i) acc[i] = (f32x4){0.f,0.f,0.f,0.f};
  for (int kc = 0; kc < 4; ++kc){
    { // stage A chunk: rows n = t>>2 are own-wave; in-order within wave
      int n = t >> 2, q = t & 3;
      if (kc < 2){
        float* sp = agg + (size_t)(nb+n)*H + kc*32 + q*8;
        float4 v0 = *(const float4*)sp;
        float4 v1 = *(const float4*)(sp + 4);
        float4 b0 = *(const float4*)&bconv[kc*32 + q*8];
        float4 b1 = *(const float4*)&bconv[kc*32 + q*8 + 4];
        *(float4*)sp       = make_float4(0.f,0.f,0.f,0.f);
        *(float4*)(sp + 4) = make_float4(0.f,0.f,0.f,0.f);
        float vals[8] = { fmaxf(v0.x+b0.x,0.f), fmaxf(v0.y+b0.y,0.f),
                          fmaxf(v0.z+b0.z,0.f), fmaxf(v0.w+b0.w,0.f),
                          fmaxf(v1.x+b1.x,0.f), fmaxf(v1.y+b1.y,0.f),
                          fmaxf(v1.z+b1.z,0.f), fmaxf(v1.w+b1.w,0.f) };
        union { bf16x8 v; u16 u[8]; } ph, pl;
        #pragma unroll
        for (int j = 0; j < 8; ++j){
          u16 hi = bf_hi(vals[j]);
          ph.u[j] = hi; pl.u[j] = bf_lo(vals[j], hi);
        }
        *(bf16x8*)&Ah[n][q*8] = ph.v;
        *(bf16x8*)&Al[n][q*8] = pl.v;
      } else {
        int gofs = (nb+n)*H + (kc-2)*32 + q*8;
        *(bf16x8*)&Ah[n][q*8] = *(const bf16x8*)&d_xhi[gofs];
        *(bf16x8*)&Al[n][q*8] = *(const bf16x8*)&d_xlo[gofs];
      }
    }
    bf16x8 ah = *(const bf16x8*)&Ah[w*16 + m][kj];
    bf16x8 al = *(const bf16x8*)&Al[w*16 + m][kj];
    #pragma unroll
    for (int nt = 0; nt < 16; ++nt){
      bf16x8 bh = bF[(size_t)(kc*16 + nt)*64];
      acc[nt] = MFMA16(ah, bh, acc[nt]);
      acc[nt] = MFMA16(al, bh, acc[nt]);
    }
  }
  __syncthreads();   // bias LDS visible to all waves
  int q4 = lane >> 4, col0 = lane & 15;
  #pragma unroll
  for (int r = 0; r < 4; ++r){
    int node = nb + w*16 + q4*4 + r;
    #pragma unroll
    for (int j = 0; j < 4; ++j){
      int d = col0 + 16*j;
      float rg = sigmoidf_(acc[j][r]   + bih_s[d]      + bhh_s[d]);
      float z  = sigmoidf_(acc[4+j][r] + bih_s[64+d]   + bhh_s[64+d]);
      float nn = tanhf(acc[8+j][r] + bih_s[128+d] + rg*(acc[12+j][r] + bhh_s[128+d]));
      size_t off = (size_t)node*H + d;
      float hv = h[off];
      float hn = (1.f - z)*nn + z*hv;
      h[off] = hn;
      u16 hb = bf_hi(hn);
      d_xhi[off] = hb;
      d_xlo[off] = bf_lo(hn, hb);
    }
  }
}

// ==================== Bl2 pack ====================
__global__ __launch_bounds__(256) void build_bl2(
    const float* __restrict__ Wih, const float* __restrict__ Whh,
    float* __restrict__ Bl2){
  int i = blockIdx.x*256 + threadIdx.x;   // 196608
  int k = i >> 9, c = i & 511;
  int d = c >> 2, gate = c & 3;
  int row = gate*128 + d;
  float v = (k < 256) ? Wih[(size_t)row*QS + k] : Whh[(size_t)row*D2 + (k-256)];
  Bl2[i] = v;
}

// ==================== fused Set2Set step: LSTM cell + attention (512 thr) ====
__global__ __launch_bounds__(512) void s2s_kernel(
    const float* __restrict__ x0, const float* __restrict__ h,
    const float* __restrict__ Bl2, const float* __restrict__ lbih,
    const float* __restrict__ lbhh, float* __restrict__ hl,
    float* __restrict__ cl, float* __restrict__ qstar){
  __shared__ float A_s[384];
  __shared__ float part4[4][128][4];
  __shared__ float q_s[D2];
  __shared__ float alpha_s[160];
  __shared__ float wred[8];
  __shared__ float part[8][D2];
  int g = blockIdx.x, t = threadIdx.x;
  int lane = t & 63, w = t >> 6;
  if (t < 384){
    A_s[t] = (t < 256) ? qstar[(size_t)g*QS + t] : hl[(size_t)g*D2 + (t - 256)];
  }
  __syncthreads();
  {
    int d = t & 127, ks = t >> 7;
    const float* bp = Bl2 + 4*d;
    float ai = 0.f, af = 0.f, ag = 0.f, ao = 0.f;
    #pragma unroll 8
    for (int kk = 0; kk < 96; ++kk){
      int k = ks*96 + kk;
      float a = A_s[k];
      float4 b = *(const float4*)(bp + (size_t)k*512);
      ai += a*b.x; af += a*b.y; ag += a*b.z; ao += a*b.w;
    }
    *(float4*)&part4[ks][d][0] = make_float4(ai, af, ag, ao);
  }
  __syncthreads();
  if (t < D2){
    float4 p0 = *(const float4*)&part4[0][t][0];
    float4 p1 = *(const float4*)&part4[1][t][0];
    float4 p2 = *(const float4*)&part4[2][t][0];
    float4 p3 = *(const float4*)&part4[3][t][0];
    float iv = p0.x+p1.x+p2.x+p3.x + lbih[t]       + lbhh[t];
    float fv = p0.y+p1.y+p2.y+p3.y + lbih[128 + t] + lbhh[128 + t];
    float gv = p0.z+p1.z+p2.z+p3.z + lbih[256 + t] + lbhh[256 + t];
    float ov = p0.w+p1.w+p2.w+p3.w + lbih[384 + t] + lbhh[384 + t];
    float c = sigmoidf_(fv)*cl[(size_t)g*D2 + t] + sigmoidf_(iv)*tanhf(gv);
    float hn = sigmoidf_(ov)*tanhf(c);
    cl[(size_t)g*D2 + t] = c;
    hl[(size_t)g*D2 + t] = hn;
    q_s[t] = hn;
  }
  __syncthreads();
  int n0 = (g*N_NODES + N_GRAPHS - 1)/N_GRAPHS;
  int n1 = ((g+1)*N_NODES + N_GRAPHS - 1)/N_GRAPHS;
  int cnt = n1 - n0;
  float e = -1e30f;
  if (t < cnt){
    int n = n0 + t;
    const float4* xr = (const float4*)(x0 + (size_t)n*H);
    const float4* hr = (const float4*)(h  + (size_t)n*H);
    const float4* q1 = (const float4*)q_s;
    const float4* q2 = (const float4*)(q_s + H);
    float s = 0.0f;
    #pragma unroll
    for (int k4 = 0; k4 < 16; ++k4){
      float4 a = xr[k4], b = q1[k4];
      s += a.x*b.x + a.y*b.y + a.z*b.z + a.w*b.w;
    }
    #pragma unroll
    for (int k4 = 0; k4 < 16; ++k4){
      float4 a = hr[k4], b = q2[k4];
      s += a.x*b.x + a.y*b.y + a.z*b.z + a.w*b.w;
    }
    e = s;
  }
  float mx = e;
  #pragma unroll
  for (int off = 32; off >= 1; off >>= 1) mx = fmaxf(mx, __shfl_xor(mx, off));
  if (lane == 0) wred[w] = mx;
  __syncthreads();
  float gm = wred[0];
  #pragma unroll
  for (int i = 1; i < 8; ++i) gm = fmaxf(gm, wred[i]);
  __syncthreads();
  float ex = (t < cnt) ? expf(e - gm) : 0.0f;
  float sm = ex;
  #pragma unroll
  for (int off = 32; off >= 1; off >>= 1) sm += __shfl_xor(sm, off);
  if (lane == 0) wred[w] = sm;
  __syncthreads();
  float denom = wred[0]+wred[1]+wred[2]+wred[3]+wred[4]+wred[5]+wred[6]+wred[7];
  if (t < cnt) alpha_s[t] = ex / denom;
  __syncthreads();
  float acc0 = 0.f, acc1 = 0.f;
  for (int i = w; i < cnt; i += 8){
    float a = alpha_s[i];
    acc0 += a * x0[(size_t)(n0+i)*H + lane];
    acc1 += a * h [(size_t)(n0+i)*H + lane];
  }
  part[w][lane]      = acc0;
  part[w][64 + lane] = acc1;
  __syncthreads();
  if (t < D2){
    float v = 0.f;
    #pragma unroll
    for (int i = 0; i < 8; ++i) v += part[i][t];
    qstar[(size_t)g*QS + t]      = q_s[t];
    qstar[(size_t)g*QS + D2 + t] = v;
  }
}

// ==================== readout (coalesced, transposed weights) ====================
__global__ __launch_bounds__(256) void out_kernel(
    const float* __restrict__ qstar, const float* __restrict__ bsp,
    const float* __restrict__ prelu, float* __restrict__ out){
  __shared__ float q_s[QS];
  int g = blockIdx.x >> 1, half = blockIdx.x & 1;
  int t = threadIdx.x;
  q_s[t] = qstar[(size_t)g*QS + t];
  __syncthreads();
  int j0 = half*512 + t;
  float acc0 = bsp[j0], acc1 = bsp[j0 + 256];
  const float* wp = d_wspT + j0;
  #pragma unroll 4
  for (int k = 0; k < QS; ++k){
    float q = q_s[k];
    acc0 += q * wp[(size_t)k*1024];
    acc1 += q * wp[(size_t)k*1024 + 256];
  }
  float pw = prelu[0];
  out[(size_t)g*READOUT + j0]       = (acc0 >= 0.0f) ? acc0 : pw*acc0;
  out[(size_t)g*READOUT + j0 + 256] = (acc1 >= 0.0f) ? acc1 : pw*acc1;
}

extern "C" void kernel_launch(void* const* d_in, const int* in_sizes, int n_in,
                              void* d_out, int out_size, void* d_ws, size_t ws_size,
                              hipStream_t stream) {
  const float* node_feats = (const float*)d_in[0];
  const float* edge_feats = (const float*)d_in[1];
  const int*   esrc       = (const int*)d_in[2];
  const int*   edst       = (const int*)d_in[3];
  const float* Wproj = (const float*)d_in[5];
  const float* bproj = (const float*)d_in[6];
  const float* Wedge = (const float*)d_in[7];
  const float* bedge = (const float*)d_in[8];
  const float* bconv = (const float*)d_in[9];
  const float* gWih  = (const float*)d_in[10];
  const float* gWhh  = (const float*)d_in[11];
  const float* gbih  = (const float*)d_in[12];
  const float* gbhh  = (const float*)d_in[13];
  const float* lWih  = (const float*)d_in[14];
  const float* lWhh  = (const float*)d_in[15];
  const float* lbih  = (const float*)d_in[16];
  const float* lbhh  = (const float*)d_in[17];
  const float* Wsp   = (const float*)d_in[18];
  const float* bsp   = (const float*)d_in[19];
  const float* prelu = (const float*)d_in[20];

  float* ws    = (float*)d_ws;
  float* x0    = ws;                     // 2,560,000
  float* h     = ws + 2560000;           // 2,560,000
  float* agg   = ws + 5120000;           // 2,560,000
  float* qstar = ws + 7680000;           // 65,536
  float* hl    = qstar + 65536;          // 32,768
  float* cl    = hl + 32768;             // 32,768
  float* Bl2   = agg;                    // s2s phase reuses dead agg (196,608)

  hipMemsetAsync(qstar, 0, (65536 + 32768 + 32768)*sizeof(float), stream);

  pack_weF<<<272, 256, 0, stream>>>(Wedge, bedge);
  pack_bcF<<<128, 256, 0, stream>>>(gWih, gWhh);
  pack_wspT<<<1024, 256, 0, stream>>>(Wsp);

  proj_mm<<<N_NODES/64, 256, 0, stream>>>(node_feats, Wproj, bproj, x0, h);

  for (int s = 0; s < 3; ++s){
    if (s == 0)
      zero_buf<<<2048, 256, 0, stream>>>((float4*)agg, N_NODES*H/4);
    edge_mfma<<<N_EDGES/64, 256, 0, stream>>>(h, edge_feats, esrc, edst, agg);
    gru_mm_mfma<<<N_NODES/64, 256, 0, stream>>>(agg, bconv, h, gbih, gbhh);  // zeroes agg
  }

  build_bl2<<<768, 256, 0, stream>>>(lWih, lWhh, Bl2);

  for (int s = 0; s < 3; ++s){
    s2s_kernel<<<N_GRAPHS, 512, 0, stream>>>(x0, h, Bl2, lbih, lbhh, hl, cl, qstar);
  }

  out_kernel<<<2*N_GRAPHS, 256, 0, stream>>>(qstar, bsp, prelu, (float*)d_out);
}